// Round 3
// baseline (584.088 us; speedup 1.0000x reference)
//
#include <hip/hip_runtime.h>
#include <hip/hip_bf16.h>
#include <math.h>

// TbpNet: B=16, A=256, NBH=64, F=128, K=25, L=3.
// R2: all GEMMs + attention on MFMA bf16; filter gather coalesced.
#define NB   16
#define NA   256
#define NNBH 64
#define NF   128
#define NK   25
#define NATOM (NB*NA)   // 4096

typedef __attribute__((ext_vector_type(4))) float f32x4;
typedef __attribute__((ext_vector_type(8))) short bf16x8;

__device__ __constant__ float BINOM_C[25] = {
  1.f, 24.f, 276.f, 2024.f, 10626.f, 42504.f, 134596.f, 346104.f,
  735471.f, 1307504.f, 1961256.f, 2496144.f, 2704156.f, 2496144.f,
  1961256.f, 1307504.f, 735471.f, 346104.f, 134596.f, 42504.f,
  10626.f, 2024.f, 276.f, 24.f, 1.f
};

__device__ __forceinline__ float sspf(float x) {
  float t = (x > 20.f) ? x : log1pf(expf(x));
  return t - 0.69314718055994531f;
}
__device__ __forceinline__ unsigned short f2bf(float x) {
  __hip_bfloat16 h = __float2bfloat16(x);
  return *(unsigned short*)&h;
}

// ---------------- embedding ----------------
__global__ void k_embed(const int* __restrict__ Z, const float* __restrict__ emb,
                        float* __restrict__ x) {
  int i = blockIdx.x * 256 + threadIdx.x;
  x[i] = emb[Z[i >> 7] * NF + (i & 127)];
}

// ---------------- weight prep: W^T bf16 [18][col][k] ----------------
__global__ void k_prep(const float* __restrict__ Win, const float* __restrict__ Wf2o,
                       const float* __restrict__ Wd, const float* __restrict__ Wq,
                       const float* __restrict__ Wk, const float* __restrict__ Wv,
                       __hip_bfloat16* __restrict__ WT) {
  int idx = blockIdx.x * 256 + threadIdx.x;   // 18*16384
  int e = idx & 16383; int m = idx >> 14;
  int l = m / 6, wsel = m - l * 6;
  const float* src = (wsel == 0) ? Win : (wsel == 1) ? Wf2o : (wsel == 2) ? Wd
                    : (wsel == 3) ? Wq : (wsel == 4) ? Wk : Wv;
  int k = e >> 7, col = e & 127;
  WT[m * 16384 + col * 128 + k] = __float2bfloat16(src[l * NF * NF + k * NF + col]);
}

// ---------------- Wext f32 [L][2][32][128] for filter epilogue ----------------
__global__ void k_wext(const float* __restrict__ Wfs, const float* __restrict__ Wfp,
                       float* __restrict__ Wext) {
  int idx = blockIdx.x * 256 + threadIdx.x;     // 24576
  int f = idx & 127, kk = (idx >> 7) & 31, band = (idx >> 12) & 1, l = idx >> 13;
  float v = 0.f;
  if (kk < NK) v = (band ? Wfp : Wfs)[l * NK * NF + kk * NF + f];
  Wext[idx] = v;
}

// ---------------- register MFMA GEMM: 16 rows/block, 1 wave ----------------
// out = act( Xin(+v+n if RES) @ W + bias ); optional x_new writeback (RES)
template<int INBF, int RES, int ACT, int OBF, int OF32>
__global__ __launch_bounds__(64) void k_gemm16(
    const void* __restrict__ Xin, const float* __restrict__ vres,
    const float* __restrict__ nres, const __hip_bfloat16* __restrict__ WT,
    const float* __restrict__ bias, __hip_bfloat16* obf, float* of32,
    float* xupd) {
  int l = threadIdx.x;
  int lr = l & 15, lg = l >> 4;
  int row = blockIdx.x * 16 + lr;

  bf16x8 afr[4];
  if (INBF) {
    const __hip_bfloat16* xr = (const __hip_bfloat16*)Xin + row * NF;
    #pragma unroll
    for (int ks = 0; ks < 4; ks++)
      afr[ks] = *(const bf16x8*)(xr + ks * 32 + lg * 8);
  } else {
    const float* xr = (const float*)Xin + row * NF;
    #pragma unroll
    for (int ks = 0; ks < 4; ks++) {
      int k0 = ks * 32 + lg * 8;
      float t[8];
      #pragma unroll
      for (int j = 0; j < 8; j++) {
        float v = xr[k0 + j];
        if (RES) v += vres[row * NF + k0 + j] + nres[row * NF + k0 + j];
        t[j] = v;
      }
      if (RES) {
        #pragma unroll
        for (int j = 0; j < 8; j++) xupd[row * NF + k0 + j] = t[j];
      }
      bf16x8 a;
      #pragma unroll
      for (int j = 0; j < 8; j++) a[j] = (short)f2bf(t[j]);
      afr[ks] = a;
    }
  }

  f32x4 acc[8];
  #pragma unroll
  for (int nt = 0; nt < 8; nt++) acc[nt] = (f32x4){0.f, 0.f, 0.f, 0.f};
  #pragma unroll
  for (int ks = 0; ks < 4; ks++) {
    #pragma unroll
    for (int nt = 0; nt < 8; nt++) {
      bf16x8 bfr = *(const bf16x8*)(WT + (nt * 16 + lr) * NF + ks * 32 + lg * 8);
      acc[nt] = __builtin_amdgcn_mfma_f32_16x16x32_bf16(afr[ks], bfr, acc[nt], 0, 0, 0);
    }
  }

  #pragma unroll
  for (int nt = 0; nt < 8; nt++) {
    int col = nt * 16 + lr;
    float bv = bias ? bias[col] : 0.f;
    #pragma unroll
    for (int r = 0; r < 4; r++) {
      int orow = blockIdx.x * 16 + lg * 4 + r;
      float o = acc[nt][r] + bv;
      if (ACT) o = sspf(o);
      if (OBF) obf[orow * NF + col] = __float2bfloat16(o);
      if (OF32) of32[orow * NF + col] = o;
    }
  }
}

// ---------------- MFMA filter (per atom) ----------------
__global__ __launch_bounds__(256) void k_filter_mfma(
    const __hip_bfloat16* __restrict__ ybf, const int* __restrict__ nbrs,
    const float* __restrict__ pos, const float* __restrict__ nmask,
    const float* __restrict__ Wext, float* __restrict__ cOut) {
  __shared__ __hip_bfloat16 FFE[128 * 72];
  __shared__ __hip_bfloat16 YJT[128 * 72];
  __shared__ int jl[NNBH];
  int tid = threadIdx.x;
  int atom = blockIdx.x;
  int brow = atom & ~(NA - 1);

  for (int i = tid; i < 28 * 36; i += 256) {
    int r = i / 36;
    int band = r / 7, kk = 25 + (r - band * 7);
    int col = i - r * 36;
    ((unsigned*)FFE)[(band * 32 + kk) * 36 + col] = 0u;
  }

  if (tid < NNBH) {
    int n = tid;
    int j = nbrs[atom * NNBH + n];
    jl[n] = j;
    float px = pos[(brow + j) * 3 + 0] - pos[atom * 3 + 0];
    float py = pos[(brow + j) * 3 + 1] - pos[atom * 3 + 1];
    float pz = pos[(brow + j) * 3 + 2] - pos[atom * 3 + 2];
    float m = nmask[atom * NNBH + n];
    float r = sqrtf(px * px + py * py + pz * pz + 1e-12f) * m;
    float inv = 1.0f / (r + 1e-9f);
    float dx = px * inv, dy = py * inv, dz = pz * inv;
    float fcv = (r < 5.0f) ? (0.5f * cosf(0.62831853071795865f * r) + 0.5f) * m : 0.0f;
    float xe = expf(-r);
    float p1 = xe + 1e-10f;
    float p2 = 1.0f - xe + 1e-10f;
    float pk[25];
    float aa = 1.0f;
    #pragma unroll
    for (int k = 0; k < NK; k++) { pk[k] = BINOM_C[k] * aa; aa *= p1; }
    float bw = fcv;
    #pragma unroll
    for (int k = NK - 1; k >= 0; k--) {
      float ff = pk[k] * bw; bw *= p2;
      FFE[(     k) * 72 + n] = __float2bfloat16(ff);
      FFE[(32 + k) * 72 + n] = __float2bfloat16(ff * dx);
      FFE[(64 + k) * 72 + n] = __float2bfloat16(ff * dy);
      FFE[(96 + k) * 72 + n] = __float2bfloat16(ff * dz);
    }
  }
  __syncthreads();

  // coalesced gather: 16 threads per y-row, transposed LDS writes w/ rotation
  {
    int f0 = (tid & 15) * 8;
    int rotw = (tid & 7) * 8;
    #pragma unroll
    for (int it = 0; it < 4; it++) {
      int n = it * 16 + (tid >> 4);
      bf16x8 v8 = *(const bf16x8*)&ybf[(brow + jl[n]) * NF + f0];
      int nc = (n + rotw) & 63;
      #pragma unroll
      for (int j = 0; j < 8; j++)
        YJT[(f0 + j) * 72 + nc] = *((__hip_bfloat16*)&v8 + j);
    }
  }
  __syncthreads();

  int lane = tid & 63, w = tid >> 6;
  int lr = lane & 15, lg = lane >> 4;

  f32x4 acc[8][2];
  #pragma unroll
  for (int mt = 0; mt < 8; mt++)
    #pragma unroll
    for (int nt = 0; nt < 2; nt++) acc[mt][nt] = (f32x4){0.f, 0.f, 0.f, 0.f};

  int f0b = 32 * w + lr;
  int f1b = f0b + 16;
  int r0 = ((f0b >> 3) & 7) * 8;
  int r1 = ((f1b >> 3) & 7) * 8;
  #pragma unroll
  for (int s = 0; s < 2; s++) {
    int n0 = lg * 8 + s * 32;
    bf16x8 b0 = *(bf16x8*)&YJT[f0b * 72 + ((n0 + r0) & 63)];
    bf16x8 b1 = *(bf16x8*)&YJT[f1b * 72 + ((n0 + r1) & 63)];
    #pragma unroll
    for (int mt = 0; mt < 8; mt++) {
      bf16x8 af = *(bf16x8*)((char*)FFE + (16 * mt + lr) * 144 + lg * 16 + s * 64);
      acc[mt][0] = __builtin_amdgcn_mfma_f32_16x16x32_bf16(af, b0, acc[mt][0], 0, 0, 0);
      acc[mt][1] = __builtin_amdgcn_mfma_f32_16x16x32_bf16(af, b1, acc[mt][1], 0, 0, 0);
    }
  }

  #pragma unroll
  for (int nt = 0; nt < 2; nt++) {
    int f = 32 * w + 16 * nt + lr;
    float ps = 0.f, pp0 = 0.f, pp1 = 0.f, pp2 = 0.f;
    #pragma unroll
    for (int mt = 0; mt < 8; mt++) {
      const float* wrow = Wext + ((mt >> 1) ? (32 * NF) : 0) + (16 * (mt & 1) + 4 * lg) * NF + f;
      #pragma unroll
      for (int jj = 0; jj < 4; jj++) {
        float t = wrow[jj * NF] * acc[mt][nt][jj];
        if      ((mt >> 1) == 0) ps  += t;
        else if ((mt >> 1) == 1) pp0 += t;
        else if ((mt >> 1) == 2) pp1 += t;
        else                     pp2 += t;
      }
    }
    ps  += __shfl_xor(ps, 16);  ps  += __shfl_xor(ps, 32);
    pp0 += __shfl_xor(pp0, 16); pp0 += __shfl_xor(pp0, 32);
    pp1 += __shfl_xor(pp1, 16); pp1 += __shfl_xor(pp1, 32);
    pp2 += __shfl_xor(pp2, 16); pp2 += __shfl_xor(pp2, 32);
    if (lg == 0)
      cOut[atom * NF + f] = ps + pp0 * pp0 + pp1 * pp1 + pp2 * pp2;
  }
}

// ---------------- fused MFMA attention (per batch): QKV + flash + n out ----------------
__global__ __launch_bounds__(512, 2) void k_attn_mfma(
    const float* __restrict__ x, const float* __restrict__ amask,
    const __hip_bfloat16* __restrict__ WTq, const __hip_bfloat16* __restrict__ WTk,
    const __hip_bfloat16* __restrict__ WTv,
    __hip_bfloat16* __restrict__ Kw, __hip_bfloat16* __restrict__ Vw,
    float* __restrict__ nout) {
  __shared__ __hip_bfloat16 Klds[64 * 136];
  __shared__ __hip_bfloat16 Vtlds[128 * 72];
  __shared__ __hip_bfloat16 Plds[8][32 * 72];
  __shared__ __hip_bfloat16 Qs[8][32 * 136];

  int tid = threadIdx.x;
  int b = blockIdx.x;
  int w = tid >> 6, l = tid & 63;
  int lr = l & 15, lg = l >> 4;
  int q0 = w * 32;
  const float scale = 0.08838834764831845f;

  // phase 0: xm fragments (x * amask, bf16)
  bf16x8 xmf[2][4];
  #pragma unroll
  for (int mt = 0; mt < 2; mt++) {
    int row = b * NA + q0 + 16 * mt + lr;
    float am = amask[row];
    #pragma unroll
    for (int ks = 0; ks < 4; ks++) {
      int k0 = ks * 32 + lg * 8;
      float4 a = *(const float4*)&x[row * NF + k0];
      float4 c = *(const float4*)&x[row * NF + k0 + 4];
      bf16x8 t;
      t[0] = (short)f2bf(a.x * am); t[1] = (short)f2bf(a.y * am);
      t[2] = (short)f2bf(a.z * am); t[3] = (short)f2bf(a.w * am);
      t[4] = (short)f2bf(c.x * am); t[5] = (short)f2bf(c.y * am);
      t[6] = (short)f2bf(c.z * am); t[7] = (short)f2bf(c.w * am);
      xmf[mt][ks] = t;
    }
  }

  // phase 1: Q (to per-wave LDS then regs), K,V (to global ws)
  bf16x8 qf[2][4];
  {
    f32x4 acc[2][8];
    // ---- Q ----
    #pragma unroll
    for (int mt = 0; mt < 2; mt++)
      #pragma unroll
      for (int nt = 0; nt < 8; nt++) acc[mt][nt] = (f32x4){0.f,0.f,0.f,0.f};
    #pragma unroll
    for (int ks = 0; ks < 4; ks++)
      #pragma unroll
      for (int nt = 0; nt < 8; nt++) {
        bf16x8 bfr = *(const bf16x8*)(WTq + (nt * 16 + lr) * NF + ks * 32 + lg * 8);
        #pragma unroll
        for (int mt = 0; mt < 2; mt++)
          acc[mt][nt] = __builtin_amdgcn_mfma_f32_16x16x32_bf16(xmf[mt][ks], bfr, acc[mt][nt], 0, 0, 0);
      }
    #pragma unroll
    for (int mt = 0; mt < 2; mt++)
      #pragma unroll
      for (int nt = 0; nt < 8; nt++)
        #pragma unroll
        for (int r = 0; r < 4; r++)
          Qs[w][(16 * mt + 4 * lg + r) * 136 + nt * 16 + lr] = __float2bfloat16(sspf(acc[mt][nt][r]));
    #pragma unroll
    for (int mt = 0; mt < 2; mt++)
      #pragma unroll
      for (int ks = 0; ks < 4; ks++)
        qf[mt][ks] = *(const bf16x8*)&Qs[w][(16 * mt + lr) * 136 + ks * 32 + lg * 8];
    // ---- K ----
    #pragma unroll
    for (int mt = 0; mt < 2; mt++)
      #pragma unroll
      for (int nt = 0; nt < 8; nt++) acc[mt][nt] = (f32x4){0.f,0.f,0.f,0.f};
    #pragma unroll
    for (int ks = 0; ks < 4; ks++)
      #pragma unroll
      for (int nt = 0; nt < 8; nt++) {
        bf16x8 bfr = *(const bf16x8*)(WTk + (nt * 16 + lr) * NF + ks * 32 + lg * 8);
        #pragma unroll
        for (int mt = 0; mt < 2; mt++)
          acc[mt][nt] = __builtin_amdgcn_mfma_f32_16x16x32_bf16(xmf[mt][ks], bfr, acc[mt][nt], 0, 0, 0);
      }
    #pragma unroll
    for (int mt = 0; mt < 2; mt++)
      #pragma unroll
      for (int nt = 0; nt < 8; nt++)
        #pragma unroll
        for (int r = 0; r < 4; r++)
          Kw[(b * NA + q0 + 16 * mt + 4 * lg + r) * NF + nt * 16 + lr] =
            __float2bfloat16(sspf(acc[mt][nt][r]));
    // ---- V ----
    #pragma unroll
    for (int mt = 0; mt < 2; mt++)
      #pragma unroll
      for (int nt = 0; nt < 8; nt++) acc[mt][nt] = (f32x4){0.f,0.f,0.f,0.f};
    #pragma unroll
    for (int ks = 0; ks < 4; ks++)
      #pragma unroll
      for (int nt = 0; nt < 8; nt++) {
        bf16x8 bfr = *(const bf16x8*)(WTv + (nt * 16 + lr) * NF + ks * 32 + lg * 8);
        #pragma unroll
        for (int mt = 0; mt < 2; mt++)
          acc[mt][nt] = __builtin_amdgcn_mfma_f32_16x16x32_bf16(xmf[mt][ks], bfr, acc[mt][nt], 0, 0, 0);
      }
    #pragma unroll
    for (int mt = 0; mt < 2; mt++)
      #pragma unroll
      for (int nt = 0; nt < 8; nt++)
        #pragma unroll
        for (int r = 0; r < 4; r++)
          Vw[(b * NA + q0 + 16 * mt + 4 * lg + r) * NF + nt * 16 + lr] =
            __float2bfloat16(sspf(acc[mt][nt][r]));
  }
  __syncthreads();

  // phase 2: flash over 4 key-chunks of 64
  f32x4 O[2][8];
  #pragma unroll
  for (int mt = 0; mt < 2; mt++)
    #pragma unroll
    for (int nt = 0; nt < 8; nt++) O[mt][nt] = (f32x4){0.f,0.f,0.f,0.f};
  float mrun[2][4], srun[2][4];
  #pragma unroll
  for (int mt = 0; mt < 2; mt++)
    #pragma unroll
    for (int r = 0; r < 4; r++) { mrun[mt][r] = -1e30f; srun[mt][r] = 0.f; }

  for (int kc = 0; kc < 4; kc++) {
    // stage K chunk + V^T chunk
    #pragma unroll
    for (int it = 0; it < 2; it++) {
      int e = it * 512 + tid;
      int krow = e >> 4, f0 = (e & 15) * 8;
      *(bf16x8*)&Klds[krow * 136 + f0] = *(const bf16x8*)&Kw[(b * NA + kc * 64 + krow) * NF + f0];
      bf16x8 v8 = *(const bf16x8*)&Vw[(b * NA + kc * 64 + krow) * NF + f0];
      int vrot = (e & 7) * 8;
      int colv = (krow + vrot) & 63;
      #pragma unroll
      for (int j = 0; j < 8; j++)
        Vtlds[(f0 + j) * 72 + colv] = *((__hip_bfloat16*)&v8 + j);
    }
    __syncthreads();

    // S chunk [32q x 64key]
    f32x4 sacc[2][4];
    #pragma unroll
    for (int mt = 0; mt < 2; mt++)
      #pragma unroll
      for (int ntc = 0; ntc < 4; ntc++) sacc[mt][ntc] = (f32x4){0.f,0.f,0.f,0.f};
    #pragma unroll
    for (int ks = 0; ks < 4; ks++)
      #pragma unroll
      for (int ntc = 0; ntc < 4; ntc++) {
        bf16x8 bfr = *(const bf16x8*)&Klds[(ntc * 16 + lr) * 136 + ks * 32 + lg * 8];
        #pragma unroll
        for (int mt = 0; mt < 2; mt++)
          sacc[mt][ntc] = __builtin_amdgcn_mfma_f32_16x16x32_bf16(qf[mt][ks], bfr, sacc[mt][ntc], 0, 0, 0);
      }

    float kam[4];
    #pragma unroll
    for (int ntc = 0; ntc < 4; ntc++)
      kam[ntc] = (1.0f - amask[b * NA + kc * 64 + ntc * 16 + lr]) * (-1e9f);

    float plv[2][4][4];
    #pragma unroll
    for (int mt = 0; mt < 2; mt++) {
      #pragma unroll
      for (int r = 0; r < 4; r++) {
        float lv[4];
        float cm = -1e30f;
        #pragma unroll
        for (int ntc = 0; ntc < 4; ntc++) {
          lv[ntc] = sacc[mt][ntc][r] * scale + kam[ntc];
          cm = fmaxf(cm, lv[ntc]);
        }
        cm = fmaxf(cm, __shfl_xor(cm, 1)); cm = fmaxf(cm, __shfl_xor(cm, 2));
        cm = fmaxf(cm, __shfl_xor(cm, 4)); cm = fmaxf(cm, __shfl_xor(cm, 8));
        float mold = mrun[mt][r];
        float mnew = fmaxf(mold, cm);
        float fr = expf(mold - mnew);
        float ps = 0.f;
        #pragma unroll
        for (int ntc = 0; ntc < 4; ntc++) {
          float p = expf(lv[ntc] - mnew);
          plv[mt][ntc][r] = p;
          ps += p;
        }
        ps += __shfl_xor(ps, 1); ps += __shfl_xor(ps, 2);
        ps += __shfl_xor(ps, 4); ps += __shfl_xor(ps, 8);
        srun[mt][r] = srun[mt][r] * fr + ps;
        mrun[mt][r] = mnew;
        #pragma unroll
        for (int nt = 0; nt < 8; nt++) O[mt][nt][r] *= fr;
      }
    }
    // P -> per-wave LDS, read back as A-frags
    #pragma unroll
    for (int mt = 0; mt < 2; mt++)
      #pragma unroll
      for (int ntc = 0; ntc < 4; ntc++)
        #pragma unroll
        for (int r = 0; r < 4; r++)
          Plds[w][(16 * mt + 4 * lg + r) * 72 + ntc * 16 + lr] = __float2bfloat16(plv[mt][ntc][r]);
    bf16x8 pf[2][2];
    #pragma unroll
    for (int mt = 0; mt < 2; mt++)
      #pragma unroll
      for (int ki = 0; ki < 2; ki++)
        pf[mt][ki] = *(const bf16x8*)&Plds[w][(16 * mt + lr) * 72 + ki * 32 + lg * 8];
    // PV
    #pragma unroll
    for (int ki = 0; ki < 2; ki++)
      #pragma unroll
      for (int nt = 0; nt < 8; nt++) {
        int f = nt * 16 + lr;
        int rot = ((f >> 3) & 7) * 8;
        int n0 = (ki * 32 + lg * 8 + rot) & 63;
        bf16x8 bfr = *(const bf16x8*)&Vtlds[f * 72 + n0];
        #pragma unroll
        for (int mt = 0; mt < 2; mt++)
          O[mt][nt] = __builtin_amdgcn_mfma_f32_16x16x32_bf16(pf[mt][ki], bfr, O[mt][nt], 0, 0, 0);
      }
    __syncthreads();
  }

  // finalize: n = O/srun * amask_q
  #pragma unroll
  for (int mt = 0; mt < 2; mt++)
    #pragma unroll
    for (int r = 0; r < 4; r++) {
      int q = b * NA + q0 + 16 * mt + 4 * lg + r;
      float inv = amask[q] / srun[mt][r];
      #pragma unroll
      for (int nt = 0; nt < 8; nt++)
        nout[q * NF + nt * 16 + lr] = O[mt][nt][r] * inv;
    }
}

// ---------------- final combine ----------------
__global__ void k_combine(float* __restrict__ x, const float* __restrict__ v,
                          const float* __restrict__ n) {
  int i = blockIdx.x * 256 + threadIdx.x;
  x[i] += v[i] + n[i];
}

// ---------------- host launch ----------------
extern "C" void kernel_launch(void* const* d_in, const int* in_sizes, int n_in,
                              void* d_out, int out_size, void* d_ws, size_t ws_size,
                              hipStream_t stream) {
  const float* pos   = (const float*)d_in[0];
  const float* nmask = (const float*)d_in[1];
  const float* amask = (const float*)d_in[2];
  const float* emb   = (const float*)d_in[3];
  const float* Wfs   = (const float*)d_in[4];
  const float* Wfp   = (const float*)d_in[5];
  const float* Win   = (const float*)d_in[6];
  const float* Wf2o  = (const float*)d_in[7];
  const float* bf2o  = (const float*)d_in[8];
  const float* Wd    = (const float*)d_in[9];
  const float* bd    = (const float*)d_in[10];
  const float* Wq    = (const float*)d_in[11];
  const float* Wk    = (const float*)d_in[12];
  const float* Wv    = (const float*)d_in[13];
  const int*   Z     = (const int*)d_in[14];
  const int*   nbrs  = (const int*)d_in[15];

  float* x = (float*)d_out;
  float* wsf = (float*)d_ws;
  const int S = NATOM * NF;                 // 524288
  float* Cb  = wsf;                         // c (f32)
  float* Vb  = wsf + S;                     // v (f32)
  float* Nb  = wsf + 2 * S;                 // n (f32)
  __hip_bfloat16* hb  = (__hip_bfloat16*)(wsf + 3 * S);            // h bf16
  __hip_bfloat16* ybf = (__hip_bfloat16*)(wsf + 3 * S + S / 2);    // y bf16
  __hip_bfloat16* Kw  = (__hip_bfloat16*)(wsf + 4 * S);            // K bf16
  __hip_bfloat16* Vw  = (__hip_bfloat16*)(wsf + 4 * S + S / 2);    // V bf16
  __hip_bfloat16* WT  = (__hip_bfloat16*)(wsf + 5 * S);            // 18*16384 bf16
  float* Wext = wsf + 5 * S + 18 * 16384 / 2;                      // 24576 f32

  k_prep<<<dim3(1152), dim3(256), 0, stream>>>(Win, Wf2o, Wd, Wq, Wk, Wv, WT);
  k_wext<<<dim3(96), dim3(256), 0, stream>>>(Wfs, Wfp, Wext);
  k_embed<<<dim3(NATOM * NF / 256), dim3(256), 0, stream>>>(Z, emb, x);

  for (int l = 0; l < 3; l++) {
    const __hip_bfloat16* WTin  = WT + (l * 6 + 0) * 16384;
    const __hip_bfloat16* WTf2o = WT + (l * 6 + 1) * 16384;
    const __hip_bfloat16* WTd   = WT + (l * 6 + 2) * 16384;
    const __hip_bfloat16* WTq   = WT + (l * 6 + 3) * 16384;
    const __hip_bfloat16* WTk   = WT + (l * 6 + 4) * 16384;
    const __hip_bfloat16* WTv   = WT + (l * 6 + 5) * 16384;
    const float* Wext_l = Wext + l * 2 * 32 * NF;

    // y = (x [+v+n]) @ Win -> bf16 (and x update for l>0)
    if (l == 0)
      k_gemm16<0,0,0,1,0><<<dim3(256), dim3(64), 0, stream>>>(
          x, nullptr, nullptr, WTin, nullptr, ybf, nullptr, nullptr);
    else
      k_gemm16<0,1,0,1,0><<<dim3(256), dim3(64), 0, stream>>>(
          x, Vb, Nb, WTin, nullptr, ybf, nullptr, x);
    // c
    k_filter_mfma<<<dim3(NATOM), dim3(256), 0, stream>>>(ybf, nbrs, pos, nmask, Wext_l, Cb);
    // h = ssp(c @ Wf2o + b) -> bf16
    k_gemm16<0,0,1,1,0><<<dim3(256), dim3(64), 0, stream>>>(
        Cb, nullptr, nullptr, WTf2o, bf2o + l * NF, hb, nullptr, nullptr);
    // v = h @ Wd + b -> f32
    k_gemm16<1,0,0,0,1><<<dim3(256), dim3(64), 0, stream>>>(
        hb, nullptr, nullptr, WTd, bd + l * NF, nullptr, Vb, nullptr);
    // attention -> n
    k_attn_mfma<<<dim3(NB), dim3(512), 0, stream>>>(
        x, amask, WTq, WTk, WTv, Kw, Vw, Nb);
  }
  k_combine<<<dim3(NATOM * NF / 256), dim3(256), 0, stream>>>(x, Vb, Nb);
}

// Round 4
// 313.082 us; speedup vs baseline: 1.8656x; 1.8656x over previous
//
#include <hip/hip_runtime.h>
#include <hip/hip_bf16.h>
#include <math.h>

// TbpNet: B=16, A=256, NBH=64, F=128, K=25, L=3.
// R3: attention re-gridded (64 blocks flash + QKV via 16-row GEMM);
//     filter geometry parallelized (exp2 form) + epilogue loads coalesced.
#define NB   16
#define NA   256
#define NNBH 64
#define NF   128
#define NK   25
#define NATOM (NB*NA)   // 4096

typedef __attribute__((ext_vector_type(4))) float f32x4;
typedef __attribute__((ext_vector_type(8))) short bf16x8;

__device__ __constant__ float BINOM_C[25] = {
  1.f, 24.f, 276.f, 2024.f, 10626.f, 42504.f, 134596.f, 346104.f,
  735471.f, 1307504.f, 1961256.f, 2496144.f, 2704156.f, 2496144.f,
  1961256.f, 1307504.f, 735471.f, 346104.f, 134596.f, 42504.f,
  10626.f, 2024.f, 276.f, 24.f, 1.f
};

__device__ __forceinline__ float sspf(float x) {
  float t = (x > 20.f) ? x : log1pf(expf(x));
  return t - 0.69314718055994531f;
}
__device__ __forceinline__ unsigned short f2bf(float x) {
  __hip_bfloat16 h = __float2bfloat16(x);
  return *(unsigned short*)&h;
}

// ---------------- embedding ----------------
__global__ void k_embed(const int* __restrict__ Z, const float* __restrict__ emb,
                        float* __restrict__ x) {
  int i = blockIdx.x * 256 + threadIdx.x;
  x[i] = emb[Z[i >> 7] * NF + (i & 127)];
}

// ---------------- weight prep: W^T bf16 [18][col][k] ----------------
__global__ void k_prep(const float* __restrict__ Win, const float* __restrict__ Wf2o,
                       const float* __restrict__ Wd, const float* __restrict__ Wq,
                       const float* __restrict__ Wk, const float* __restrict__ Wv,
                       __hip_bfloat16* __restrict__ WT) {
  int idx = blockIdx.x * 256 + threadIdx.x;   // 18*16384
  int e = idx & 16383; int m = idx >> 14;
  int l = m / 6, wsel = m - l * 6;
  const float* src = (wsel == 0) ? Win : (wsel == 1) ? Wf2o : (wsel == 2) ? Wd
                    : (wsel == 3) ? Wq : (wsel == 4) ? Wk : Wv;
  int k = e >> 7, col = e & 127;
  WT[m * 16384 + col * 128 + k] = __float2bfloat16(src[l * NF * NF + k * NF + col]);
}

// ---------------- WextT f32 [L][128 f][2 band][32 k] ----------------
__global__ void k_wextT(const float* __restrict__ Wfs, const float* __restrict__ Wfp,
                        float* __restrict__ WextT) {
  int idx = blockIdx.x * 256 + threadIdx.x;     // 24576
  int k = idx & 31, s = (idx >> 5) & 1, f = (idx >> 6) & 127, l = idx >> 13;
  float v = 0.f;
  if (k < NK) v = (s ? Wfp : Wfs)[l * NK * NF + k * NF + f];
  WextT[idx] = v;
}

// ---------------- register MFMA GEMM body: 16 rows per wave ----------------
template<int INBF, int MASKIN, int RES, int ACT, int OBF, int OF32>
__device__ __forceinline__ void gemm16_body(
    const void* __restrict__ Xin, const float* __restrict__ amask,
    const float* __restrict__ vres, const float* __restrict__ nres,
    const __hip_bfloat16* __restrict__ WT, const float* __restrict__ bias,
    __hip_bfloat16* obf, float* of32, float* xupd) {
  int l = threadIdx.x;
  int lr = l & 15, lg = l >> 4;
  int row = blockIdx.x * 16 + lr;

  bf16x8 afr[4];
  if (INBF) {
    const __hip_bfloat16* xr = (const __hip_bfloat16*)Xin + row * NF;
    #pragma unroll
    for (int ks = 0; ks < 4; ks++)
      afr[ks] = *(const bf16x8*)(xr + ks * 32 + lg * 8);
  } else {
    const float* xr = (const float*)Xin + row * NF;
    float am = MASKIN ? amask[row] : 1.0f;
    #pragma unroll
    for (int ks = 0; ks < 4; ks++) {
      int k0 = ks * 32 + lg * 8;
      float t[8];
      #pragma unroll
      for (int j = 0; j < 8; j++) {
        float v = xr[k0 + j];
        if (RES) v += vres[row * NF + k0 + j] + nres[row * NF + k0 + j];
        if (MASKIN) v *= am;
        t[j] = v;
      }
      if (RES) {
        #pragma unroll
        for (int j = 0; j < 8; j++) xupd[row * NF + k0 + j] = t[j];
      }
      bf16x8 a;
      #pragma unroll
      for (int j = 0; j < 8; j++) a[j] = (short)f2bf(t[j]);
      afr[ks] = a;
    }
  }

  f32x4 acc[8];
  #pragma unroll
  for (int nt = 0; nt < 8; nt++) acc[nt] = (f32x4){0.f, 0.f, 0.f, 0.f};
  #pragma unroll
  for (int ks = 0; ks < 4; ks++) {
    #pragma unroll
    for (int nt = 0; nt < 8; nt++) {
      bf16x8 bfr = *(const bf16x8*)(WT + (nt * 16 + lr) * NF + ks * 32 + lg * 8);
      acc[nt] = __builtin_amdgcn_mfma_f32_16x16x32_bf16(afr[ks], bfr, acc[nt], 0, 0, 0);
    }
  }

  #pragma unroll
  for (int nt = 0; nt < 8; nt++) {
    int col = nt * 16 + lr;
    float bv = bias ? bias[col] : 0.f;
    #pragma unroll
    for (int r = 0; r < 4; r++) {
      int orow = blockIdx.x * 16 + lg * 4 + r;
      float o = acc[nt][r] + bv;
      if (ACT) o = sspf(o);
      if (OBF) obf[orow * NF + col] = __float2bfloat16(o);
      if (OF32) of32[orow * NF + col] = o;
    }
  }
}

template<int INBF, int RES, int ACT, int OBF, int OF32>
__global__ __launch_bounds__(64) void k_gemm16(
    const void* __restrict__ Xin, const float* __restrict__ vres,
    const float* __restrict__ nres, const __hip_bfloat16* __restrict__ WT,
    const float* __restrict__ bias, __hip_bfloat16* obf, float* of32,
    float* xupd) {
  gemm16_body<INBF, 0, RES, ACT, OBF, OF32>(Xin, nullptr, vres, nres, WT, bias, obf, of32, xupd);
}

__global__ __launch_bounds__(64) void k_gemm16_qkv(
    const float* __restrict__ x, const float* __restrict__ amask,
    const __hip_bfloat16* __restrict__ WTq, const __hip_bfloat16* __restrict__ WTk,
    const __hip_bfloat16* __restrict__ WTv,
    __hip_bfloat16* Qw, __hip_bfloat16* Kw, __hip_bfloat16* Vw) {
  int z = blockIdx.y;
  const __hip_bfloat16* WT = (z == 0) ? WTq : (z == 1) ? WTk : WTv;
  __hip_bfloat16* out = (z == 0) ? Qw : (z == 1) ? Kw : Vw;
  gemm16_body<0, 1, 0, 1, 1, 0>(x, amask, nullptr, nullptr, WT, nullptr, out, nullptr, nullptr);
}

// ---------------- MFMA filter (per atom) ----------------
__global__ __launch_bounds__(256) void k_filter_mfma(
    const __hip_bfloat16* __restrict__ ybf, const int* __restrict__ nbrs,
    const float* __restrict__ pos, const float* __restrict__ nmask,
    const float* __restrict__ WextT, float* __restrict__ cOut) {
  __shared__ __hip_bfloat16 FFE[128 * 72];
  __shared__ __hip_bfloat16 YJT[128 * 72];
  __shared__ int jl[NNBH];
  __shared__ float fcl[NNBH], l1l[NNBH], l2l[NNBH];
  __shared__ float d3l[NNBH][4];
  __shared__ float lb2l[NK];
  int tid = threadIdx.x;
  int atom = blockIdx.x;
  int brow = atom & ~(NA - 1);

  // zero band pad rows (k 25..31 of each band)
  for (int i = tid; i < 28 * 36; i += 256) {
    int r = i / 36;
    int band = r / 7, kk = 25 + (r - band * 7);
    int col = i - r * 36;
    ((unsigned*)FFE)[(band * 32 + kk) * 36 + col] = 0u;
  }
  if (tid >= 64 && tid < 64 + NK) lb2l[tid - 64] = log2f(BINOM_C[tid - 64]);

  // geometry (64 threads)
  if (tid < NNBH) {
    int n = tid;
    int j = nbrs[atom * NNBH + n];
    jl[n] = j;
    float px = pos[(brow + j) * 3 + 0] - pos[atom * 3 + 0];
    float py = pos[(brow + j) * 3 + 1] - pos[atom * 3 + 1];
    float pz = pos[(brow + j) * 3 + 2] - pos[atom * 3 + 2];
    float m = nmask[atom * NNBH + n];
    float r = sqrtf(px * px + py * py + pz * pz + 1e-12f) * m;
    float inv = 1.0f / (r + 1e-9f);
    float fcv = (r < 5.0f) ? (0.5f * cosf(0.62831853071795865f * r) + 0.5f) * m : 0.0f;
    float xe = expf(-r);
    fcl[n] = fcv;
    l1l[n] = log2f(xe + 1e-10f);
    l2l[n] = log2f(1.0f - xe + 1e-10f);
    d3l[n][0] = 1.0f;
    d3l[n][1] = px * inv;
    d3l[n][2] = py * inv;
    d3l[n][3] = pz * inv;
  }
  __syncthreads();

  // FFE fill: all 256 threads (n = tid&63, band = tid>>6)
  {
    int n = tid & 63, band = tid >> 6;
    float fc_ = fcl[n] * d3l[n][band];
    float l1 = l1l[n], l2 = l2l[n];
    #pragma unroll
    for (int k = 0; k < NK; k++) {
      float v = exp2f(lb2l[k] + (float)k * l1 + (float)(24 - k) * l2) * fc_;
      FFE[(band * 32 + k) * 72 + n] = __float2bfloat16(v);
    }
  }

  // coalesced gather: 16 threads per y-row, transposed LDS writes w/ rotation
  {
    int f0 = (tid & 15) * 8;
    int rotw = (tid & 7) * 8;
    #pragma unroll
    for (int it = 0; it < 4; it++) {
      int n = it * 16 + (tid >> 4);
      bf16x8 v8 = *(const bf16x8*)&ybf[(brow + jl[n]) * NF + f0];
      int nc = (n + rotw) & 63;
      #pragma unroll
      for (int j = 0; j < 8; j++)
        YJT[(f0 + j) * 72 + nc] = *((__hip_bfloat16*)&v8 + j);
    }
  }
  __syncthreads();

  int lane = tid & 63, w = tid >> 6;
  int lr = lane & 15, lg = lane >> 4;

  f32x4 acc[8][2];
  #pragma unroll
  for (int mt = 0; mt < 8; mt++)
    #pragma unroll
    for (int nt = 0; nt < 2; nt++) acc[mt][nt] = (f32x4){0.f, 0.f, 0.f, 0.f};

  int f0b = 32 * w + lr;
  int f1b = f0b + 16;
  int r0 = ((f0b >> 3) & 7) * 8;
  int r1 = ((f1b >> 3) & 7) * 8;
  #pragma unroll
  for (int s = 0; s < 2; s++) {
    int n0 = lg * 8 + s * 32;
    bf16x8 b0 = *(bf16x8*)&YJT[f0b * 72 + ((n0 + r0) & 63)];
    bf16x8 b1 = *(bf16x8*)&YJT[f1b * 72 + ((n0 + r1) & 63)];
    #pragma unroll
    for (int mt = 0; mt < 8; mt++) {
      bf16x8 af = *(bf16x8*)((char*)FFE + (16 * mt + lr) * 144 + lg * 16 + s * 64);
      acc[mt][0] = __builtin_amdgcn_mfma_f32_16x16x32_bf16(af, b0, acc[mt][0], 0, 0, 0);
      acc[mt][1] = __builtin_amdgcn_mfma_f32_16x16x32_bf16(af, b1, acc[mt][1], 0, 0, 0);
    }
  }

  // epilogue: per-f contiguous weight rows WextT[f][band(2)][32]
  #pragma unroll
  for (int nt = 0; nt < 2; nt++) {
    int f = 32 * w + 16 * nt + lr;
    const float* wb = WextT + f * 64;
    float ps = 0.f, pp0 = 0.f, pp1 = 0.f, pp2 = 0.f;
    #pragma unroll
    for (int mt = 0; mt < 8; mt++) {
      float4 w4 = *(const float4*)&wb[(mt >> 1 ? 32 : 0) + 16 * (mt & 1) + 4 * lg];
      float t0 = w4.x * acc[mt][nt][0];
      float t1 = w4.y * acc[mt][nt][1];
      float t2 = w4.z * acc[mt][nt][2];
      float t3 = w4.w * acc[mt][nt][3];
      float t = t0 + t1 + t2 + t3;
      if      ((mt >> 1) == 0) ps  += t;
      else if ((mt >> 1) == 1) pp0 += t;
      else if ((mt >> 1) == 2) pp1 += t;
      else                     pp2 += t;
    }
    ps  += __shfl_xor(ps, 16);  ps  += __shfl_xor(ps, 32);
    pp0 += __shfl_xor(pp0, 16); pp0 += __shfl_xor(pp0, 32);
    pp1 += __shfl_xor(pp1, 16); pp1 += __shfl_xor(pp1, 32);
    pp2 += __shfl_xor(pp2, 16); pp2 += __shfl_xor(pp2, 32);
    if (lg == 0)
      cOut[atom * NF + f] = ps + pp0 * pp0 + pp1 * pp1 + pp2 * pp2;
  }
}

// ---------------- flash attention: 64 blocks (b x 4 q-tiles), 256 thr ----------------
__global__ __launch_bounds__(256) void k_attn2(
    const __hip_bfloat16* __restrict__ Qw, const __hip_bfloat16* __restrict__ Kw,
    const __hip_bfloat16* __restrict__ Vw, const float* __restrict__ amask,
    float* __restrict__ nout) {
  __shared__ __hip_bfloat16 Klds[64 * 136];
  __shared__ __hip_bfloat16 Vtlds[128 * 72];
  __shared__ __hip_bfloat16 Plds[4][16 * 72];
  int tid = threadIdx.x;
  int b = blockIdx.x >> 2;
  int q0 = (blockIdx.x & 3) * 64;
  int w = tid >> 6, l = tid & 63;
  int lr = l & 15, lg = l >> 4;
  int qbase = b * NA + q0 + w * 16;
  const float scale = 0.08838834764831845f;

  bf16x8 qf[4];
  #pragma unroll
  for (int ks = 0; ks < 4; ks++)
    qf[ks] = *(const bf16x8*)&Qw[(qbase + lr) * NF + ks * 32 + lg * 8];

  f32x4 O[8];
  #pragma unroll
  for (int nt = 0; nt < 8; nt++) O[nt] = (f32x4){0.f, 0.f, 0.f, 0.f};
  float mrun[4], srun[4];
  #pragma unroll
  for (int r = 0; r < 4; r++) { mrun[r] = -1e30f; srun[r] = 0.f; }

  for (int kc = 0; kc < 4; kc++) {
    // stage K chunk [64x136] + V^T chunk [128x72 rotated]
    #pragma unroll
    for (int it = 0; it < 4; it++) {
      int e = it * 256 + tid;
      int krow = e >> 4, f0 = (e & 15) * 8;
      *(bf16x8*)&Klds[krow * 136 + f0] = *(const bf16x8*)&Kw[(b * NA + kc * 64 + krow) * NF + f0];
      bf16x8 v8 = *(const bf16x8*)&Vw[(b * NA + kc * 64 + krow) * NF + f0];
      int vrot = (e & 7) * 8;
      int colv = (krow + vrot) & 63;
      #pragma unroll
      for (int j = 0; j < 8; j++)
        Vtlds[(f0 + j) * 72 + colv] = *((__hip_bfloat16*)&v8 + j);
    }
    __syncthreads();

    // S chunk [16q x 64key]
    f32x4 sacc[4];
    #pragma unroll
    for (int ntc = 0; ntc < 4; ntc++) sacc[ntc] = (f32x4){0.f, 0.f, 0.f, 0.f};
    #pragma unroll
    for (int ks = 0; ks < 4; ks++)
      #pragma unroll
      for (int ntc = 0; ntc < 4; ntc++) {
        bf16x8 bfr = *(const bf16x8*)&Klds[(ntc * 16 + lr) * 136 + ks * 32 + lg * 8];
        sacc[ntc] = __builtin_amdgcn_mfma_f32_16x16x32_bf16(qf[ks], bfr, sacc[ntc], 0, 0, 0);
      }

    float kam[4];
    #pragma unroll
    for (int ntc = 0; ntc < 4; ntc++)
      kam[ntc] = (1.0f - amask[b * NA + kc * 64 + ntc * 16 + lr]) * (-1e9f);

    float plv[4][4];
    #pragma unroll
    for (int r = 0; r < 4; r++) {
      float lv[4];
      float cm = -1e30f;
      #pragma unroll
      for (int ntc = 0; ntc < 4; ntc++) {
        lv[ntc] = sacc[ntc][r] * scale + kam[ntc];
        cm = fmaxf(cm, lv[ntc]);
      }
      cm = fmaxf(cm, __shfl_xor(cm, 1)); cm = fmaxf(cm, __shfl_xor(cm, 2));
      cm = fmaxf(cm, __shfl_xor(cm, 4)); cm = fmaxf(cm, __shfl_xor(cm, 8));
      float mold = mrun[r];
      float mnew = fmaxf(mold, cm);
      float fr = expf(mold - mnew);
      float ps = 0.f;
      #pragma unroll
      for (int ntc = 0; ntc < 4; ntc++) {
        float p = expf(lv[ntc] - mnew);
        plv[ntc][r] = p;
        ps += p;
      }
      ps += __shfl_xor(ps, 1); ps += __shfl_xor(ps, 2);
      ps += __shfl_xor(ps, 4); ps += __shfl_xor(ps, 8);
      srun[r] = srun[r] * fr + ps;
      mrun[r] = mnew;
      #pragma unroll
      for (int nt = 0; nt < 8; nt++) O[nt][r] *= fr;
    }

    // P -> per-wave LDS, read back as A-frags
    #pragma unroll
    for (int ntc = 0; ntc < 4; ntc++)
      #pragma unroll
      for (int r = 0; r < 4; r++)
        Plds[w][(4 * lg + r) * 72 + ntc * 16 + lr] = __float2bfloat16(plv[ntc][r]);
    bf16x8 pf[2];
    #pragma unroll
    for (int ki = 0; ki < 2; ki++)
      pf[ki] = *(const bf16x8*)&Plds[w][lr * 72 + ki * 32 + lg * 8];
    // PV
    #pragma unroll
    for (int ki = 0; ki < 2; ki++)
      #pragma unroll
      for (int nt = 0; nt < 8; nt++) {
        int f = nt * 16 + lr;
        int rot = ((f >> 3) & 7) * 8;
        int n0 = (ki * 32 + lg * 8 + rot) & 63;
        bf16x8 bfr = *(const bf16x8*)&Vtlds[f * 72 + n0];
        O[nt] = __builtin_amdgcn_mfma_f32_16x16x32_bf16(pf[ki], bfr, O[nt], 0, 0, 0);
      }
    __syncthreads();
  }

  // n = O/srun * amask_q
  #pragma unroll
  for (int r = 0; r < 4; r++) {
    int q = qbase + 4 * lg + r;
    float inv = amask[q] / srun[r];
    #pragma unroll
    for (int nt = 0; nt < 8; nt++)
      nout[q * NF + nt * 16 + lr] = O[nt][r] * inv;
  }
}

// ---------------- final combine ----------------
__global__ void k_combine(float* __restrict__ x, const float* __restrict__ v,
                          const float* __restrict__ n) {
  int i = blockIdx.x * 256 + threadIdx.x;
  x[i] += v[i] + n[i];
}

// ---------------- host launch ----------------
extern "C" void kernel_launch(void* const* d_in, const int* in_sizes, int n_in,
                              void* d_out, int out_size, void* d_ws, size_t ws_size,
                              hipStream_t stream) {
  const float* pos   = (const float*)d_in[0];
  const float* nmask = (const float*)d_in[1];
  const float* amask = (const float*)d_in[2];
  const float* emb   = (const float*)d_in[3];
  const float* Wfs   = (const float*)d_in[4];
  const float* Wfp   = (const float*)d_in[5];
  const float* Win   = (const float*)d_in[6];
  const float* Wf2o  = (const float*)d_in[7];
  const float* bf2o  = (const float*)d_in[8];
  const float* Wd    = (const float*)d_in[9];
  const float* bd    = (const float*)d_in[10];
  const float* Wq    = (const float*)d_in[11];
  const float* Wk    = (const float*)d_in[12];
  const float* Wv    = (const float*)d_in[13];
  const int*   Z     = (const int*)d_in[14];
  const int*   nbrs  = (const int*)d_in[15];

  float* x = (float*)d_out;
  float* wsf = (float*)d_ws;
  const int S = NATOM * NF;                 // 524288
  float* Cb  = wsf;
  float* Vb  = wsf + S;
  float* Nb  = wsf + 2 * S;
  __hip_bfloat16* hb  = (__hip_bfloat16*)(wsf + 3 * S);
  __hip_bfloat16* ybf = (__hip_bfloat16*)(wsf + 3 * S + S / 2);
  __hip_bfloat16* Qw  = (__hip_bfloat16*)(wsf + 4 * S);
  __hip_bfloat16* Kw  = (__hip_bfloat16*)(wsf + 4 * S + S / 2);
  __hip_bfloat16* Vw  = (__hip_bfloat16*)(wsf + 5 * S);
  __hip_bfloat16* WT  = (__hip_bfloat16*)(wsf + 5 * S + S / 2);   // 294912 bf16
  float* WextT = wsf + 5 * S + S / 2 + 147456;                    // 24576 f32

  k_prep<<<dim3(1152), dim3(256), 0, stream>>>(Win, Wf2o, Wd, Wq, Wk, Wv, WT);
  k_wextT<<<dim3(96), dim3(256), 0, stream>>>(Wfs, Wfp, WextT);
  k_embed<<<dim3(NATOM * NF / 256), dim3(256), 0, stream>>>(Z, emb, x);

  for (int l = 0; l < 3; l++) {
    const __hip_bfloat16* WTin  = WT + (l * 6 + 0) * 16384;
    const __hip_bfloat16* WTf2o = WT + (l * 6 + 1) * 16384;
    const __hip_bfloat16* WTd   = WT + (l * 6 + 2) * 16384;
    const __hip_bfloat16* WTq   = WT + (l * 6 + 3) * 16384;
    const __hip_bfloat16* WTk   = WT + (l * 6 + 4) * 16384;
    const __hip_bfloat16* WTv   = WT + (l * 6 + 5) * 16384;
    const float* WextT_l = WextT + l * NF * 64;

    // y = (x [+v+n]) @ Win -> bf16 (and x update for l>0)
    if (l == 0)
      k_gemm16<0,0,0,1,0><<<dim3(256), dim3(64), 0, stream>>>(
          x, nullptr, nullptr, WTin, nullptr, ybf, nullptr, nullptr);
    else
      k_gemm16<0,1,0,1,0><<<dim3(256), dim3(64), 0, stream>>>(
          x, Vb, Nb, WTin, nullptr, ybf, nullptr, x);
    // c
    k_filter_mfma<<<dim3(NATOM), dim3(256), 0, stream>>>(ybf, nbrs, pos, nmask, WextT_l, Cb);
    // h = ssp(c @ Wf2o + b) -> bf16
    k_gemm16<0,0,1,1,0><<<dim3(256), dim3(64), 0, stream>>>(
        Cb, nullptr, nullptr, WTf2o, bf2o + l * NF, hb, nullptr, nullptr);
    // v = h @ Wd + b -> f32
    k_gemm16<1,0,0,0,1><<<dim3(256), dim3(64), 0, stream>>>(
        hb, nullptr, nullptr, WTd, bd + l * NF, nullptr, Vb, nullptr);
    // q,k,v projections -> bf16
    k_gemm16_qkv<<<dim3(256, 3), dim3(64), 0, stream>>>(
        x, amask, WTq, WTk, WTv, Qw, Kw, Vw);
    // flash attention -> n
    k_attn2<<<dim3(NB * 4), dim3(256), 0, stream>>>(Qw, Kw, Vw, amask, Nb);
  }
  k_combine<<<dim3(NATOM * NF / 256), dim3(256), 0, stream>>>(x, Vb, Nb);
}

// Round 5
// 288.707 us; speedup vs baseline: 2.0231x; 1.0844x over previous
//
#include <hip/hip_runtime.h>
#include <hip/hip_bf16.h>
#include <math.h>

// TbpNet: B=16, A=256, NBH=64, F=128, K=25, L=3.
// R4: filter B-frags direct-from-global (kills LDS transpose-write conflicts);
//     fused proj (y,q,k,v), fused h+v GEMM, residual folded into attention.
#define NB   16
#define NA   256
#define NNBH 64
#define NF   128
#define NK   25
#define NATOM (NB*NA)   // 4096

typedef __attribute__((ext_vector_type(4))) float f32x4;
typedef __attribute__((ext_vector_type(8))) short bf16x8;

__device__ __constant__ float BINOM_C[25] = {
  1.f, 24.f, 276.f, 2024.f, 10626.f, 42504.f, 134596.f, 346104.f,
  735471.f, 1307504.f, 1961256.f, 2496144.f, 2704156.f, 2496144.f,
  1961256.f, 1307504.f, 735471.f, 346104.f, 134596.f, 42504.f,
  10626.f, 2024.f, 276.f, 24.f, 1.f
};

__device__ __forceinline__ float sspf(float x) {
  float t = (x > 20.f) ? x : log1pf(expf(x));
  return t - 0.69314718055994531f;
}
__device__ __forceinline__ unsigned short f2bf(float x) {
  __hip_bfloat16 h = __float2bfloat16(x);
  return *(unsigned short*)&h;
}

// ---------------- embedding ----------------
__global__ void k_embed(const int* __restrict__ Z, const float* __restrict__ emb,
                        float* __restrict__ x) {
  int i = blockIdx.x * 256 + threadIdx.x;
  x[i] = emb[Z[i >> 7] * NF + (i & 127)];
}

// ---------------- weight prep: W^T bf16 [18][col][k] ----------------
__global__ void k_prep(const float* __restrict__ Win, const float* __restrict__ Wf2o,
                       const float* __restrict__ Wd, const float* __restrict__ Wq,
                       const float* __restrict__ Wk, const float* __restrict__ Wv,
                       __hip_bfloat16* __restrict__ WT) {
  int idx = blockIdx.x * 256 + threadIdx.x;   // 18*16384
  int e = idx & 16383; int m = idx >> 14;
  int l = m / 6, wsel = m - l * 6;
  const float* src = (wsel == 0) ? Win : (wsel == 1) ? Wf2o : (wsel == 2) ? Wd
                    : (wsel == 3) ? Wq : (wsel == 4) ? Wk : Wv;
  int k = e >> 7, col = e & 127;
  WT[m * 16384 + col * 128 + k] = __float2bfloat16(src[l * NF * NF + k * NF + col]);
}

// ---------------- WextT f32 [L][128 f][2 band][32 k] ----------------
__global__ void k_wextT(const float* __restrict__ Wfs, const float* __restrict__ Wfp,
                        float* __restrict__ WextT) {
  int idx = blockIdx.x * 256 + threadIdx.x;     // 24576
  int k = idx & 31, s = (idx >> 5) & 1, f = (idx >> 6) & 127, l = idx >> 13;
  float v = 0.f;
  if (k < NK) v = (s ? Wfp : Wfs)[l * NK * NF + k * NF + f];
  WextT[idx] = v;
}

// ---------------- fused projections: z=0 y, z=1 q, z=2 k, z=3 v ----------------
__global__ __launch_bounds__(64) void k_proj(
    const float* __restrict__ x, const float* __restrict__ amask,
    const __hip_bfloat16* __restrict__ WTl,
    __hip_bfloat16* __restrict__ ybf, __hip_bfloat16* __restrict__ Qw,
    __hip_bfloat16* __restrict__ Kw, __hip_bfloat16* __restrict__ Vw) {
  int z = blockIdx.y;
  const __hip_bfloat16* WT = WTl + ((z == 0) ? 0 : (z + 2)) * (NF * NF);
  __hip_bfloat16* out = (z == 0) ? ybf : (z == 1) ? Qw : (z == 2) ? Kw : Vw;
  int l = threadIdx.x, lr = l & 15, lg = l >> 4;
  int row = blockIdx.x * 16 + lr;
  float am = (z > 0) ? amask[row] : 1.0f;
  const float* xr = x + row * NF;

  bf16x8 afr[4];
  #pragma unroll
  for (int ks = 0; ks < 4; ks++) {
    int k0 = ks * 32 + lg * 8;
    float4 a = *(const float4*)&xr[k0];
    float4 c = *(const float4*)&xr[k0 + 4];
    bf16x8 t;
    t[0] = (short)f2bf(a.x * am); t[1] = (short)f2bf(a.y * am);
    t[2] = (short)f2bf(a.z * am); t[3] = (short)f2bf(a.w * am);
    t[4] = (short)f2bf(c.x * am); t[5] = (short)f2bf(c.y * am);
    t[6] = (short)f2bf(c.z * am); t[7] = (short)f2bf(c.w * am);
    afr[ks] = t;
  }

  f32x4 acc[8];
  #pragma unroll
  for (int nt = 0; nt < 8; nt++) acc[nt] = (f32x4){0.f, 0.f, 0.f, 0.f};
  #pragma unroll
  for (int ks = 0; ks < 4; ks++)
    #pragma unroll
    for (int nt = 0; nt < 8; nt++) {
      bf16x8 bfr = *(const bf16x8*)(WT + (nt * 16 + lr) * NF + ks * 32 + lg * 8);
      acc[nt] = __builtin_amdgcn_mfma_f32_16x16x32_bf16(afr[ks], bfr, acc[nt], 0, 0, 0);
    }

  #pragma unroll
  for (int nt = 0; nt < 8; nt++) {
    int col = nt * 16 + lr;
    #pragma unroll
    for (int r = 0; r < 4; r++) {
      int orow = blockIdx.x * 16 + lg * 4 + r;
      float o = acc[nt][r];
      if (z > 0) o = sspf(o);
      out[orow * NF + col] = __float2bfloat16(o);
    }
  }
}

// ---------------- fused h = ssp(c@Wf2o+b); v = h@Wd+b ----------------
__global__ __launch_bounds__(64) void k_hv(
    const float* __restrict__ Cb, const __hip_bfloat16* __restrict__ WTf2o,
    const float* __restrict__ bf2o, const __hip_bfloat16* __restrict__ WTd,
    const float* __restrict__ bd, float* __restrict__ Vb) {
  __shared__ __hip_bfloat16 Hs[16 * 136];
  int l = threadIdx.x, lr = l & 15, lg = l >> 4;
  int row = blockIdx.x * 16 + lr;
  const float* xr = Cb + row * NF;

  bf16x8 afr[4];
  #pragma unroll
  for (int ks = 0; ks < 4; ks++) {
    int k0 = ks * 32 + lg * 8;
    float4 a = *(const float4*)&xr[k0];
    float4 c = *(const float4*)&xr[k0 + 4];
    bf16x8 t;
    t[0] = (short)f2bf(a.x); t[1] = (short)f2bf(a.y);
    t[2] = (short)f2bf(a.z); t[3] = (short)f2bf(a.w);
    t[4] = (short)f2bf(c.x); t[5] = (short)f2bf(c.y);
    t[6] = (short)f2bf(c.z); t[7] = (short)f2bf(c.w);
    afr[ks] = t;
  }

  f32x4 acc[8];
  #pragma unroll
  for (int nt = 0; nt < 8; nt++) acc[nt] = (f32x4){0.f, 0.f, 0.f, 0.f};
  #pragma unroll
  for (int ks = 0; ks < 4; ks++)
    #pragma unroll
    for (int nt = 0; nt < 8; nt++) {
      bf16x8 bfr = *(const bf16x8*)(WTf2o + (nt * 16 + lr) * NF + ks * 32 + lg * 8);
      acc[nt] = __builtin_amdgcn_mfma_f32_16x16x32_bf16(afr[ks], bfr, acc[nt], 0, 0, 0);
    }
  #pragma unroll
  for (int nt = 0; nt < 8; nt++) {
    int col = nt * 16 + lr;
    float bv = bf2o[col];
    #pragma unroll
    for (int r = 0; r < 4; r++)
      Hs[(lg * 4 + r) * 136 + col] = __float2bfloat16(sspf(acc[nt][r] + bv));
  }
  __syncthreads();

  bf16x8 hfr[4];
  #pragma unroll
  for (int ks = 0; ks < 4; ks++)
    hfr[ks] = *(const bf16x8*)&Hs[lr * 136 + ks * 32 + lg * 8];
  #pragma unroll
  for (int nt = 0; nt < 8; nt++) acc[nt] = (f32x4){0.f, 0.f, 0.f, 0.f};
  #pragma unroll
  for (int ks = 0; ks < 4; ks++)
    #pragma unroll
    for (int nt = 0; nt < 8; nt++) {
      bf16x8 bfr = *(const bf16x8*)(WTd + (nt * 16 + lr) * NF + ks * 32 + lg * 8);
      acc[nt] = __builtin_amdgcn_mfma_f32_16x16x32_bf16(hfr[ks], bfr, acc[nt], 0, 0, 0);
    }
  #pragma unroll
  for (int nt = 0; nt < 8; nt++) {
    int col = nt * 16 + lr;
    float bv = bd[col];
    #pragma unroll
    for (int r = 0; r < 4; r++)
      Vb[(blockIdx.x * 16 + lg * 4 + r) * NF + col] = acc[nt][r] + bv;
  }
}

// ---------------- MFMA filter (per atom), B-frags direct from global ----------------
__global__ __launch_bounds__(256) void k_filter_mfma(
    const __hip_bfloat16* __restrict__ ybf, const int* __restrict__ nbrs,
    const float* __restrict__ pos, const float* __restrict__ nmask,
    const float* __restrict__ WextT, float* __restrict__ cOut) {
  __shared__ __hip_bfloat16 FFE[128 * 72];
  __shared__ int jrow[NNBH];
  __shared__ float fcl[NNBH], l1l[NNBH], l2l[NNBH];
  __shared__ float d3l[NNBH][4];
  __shared__ float lb2l[NK];
  int tid = threadIdx.x;
  int atom = blockIdx.x;
  int brow = atom & ~(NA - 1);
  const unsigned short* yu = (const unsigned short*)ybf;

  // zero band pad rows (k 25..31 of each band)
  for (int i = tid; i < 28 * 36; i += 256) {
    int r = i / 36;
    int band = r / 7, kk = 25 + (r - band * 7);
    int col = i - r * 36;
    ((unsigned*)FFE)[(band * 32 + kk) * 36 + col] = 0u;
  }
  if (tid >= 64 && tid < 64 + NK) lb2l[tid - 64] = log2f(BINOM_C[tid - 64]);

  // geometry (64 threads)
  if (tid < NNBH) {
    int n = tid;
    int j = nbrs[atom * NNBH + n];
    jrow[n] = (brow + j) * NF;
    float px = pos[(brow + j) * 3 + 0] - pos[atom * 3 + 0];
    float py = pos[(brow + j) * 3 + 1] - pos[atom * 3 + 1];
    float pz = pos[(brow + j) * 3 + 2] - pos[atom * 3 + 2];
    float m = nmask[atom * NNBH + n];
    float r = sqrtf(px * px + py * py + pz * pz + 1e-12f) * m;
    float inv = 1.0f / (r + 1e-9f);
    float fcv = (r < 5.0f) ? (0.5f * cosf(0.62831853071795865f * r) + 0.5f) * m : 0.0f;
    float xe = expf(-r);
    fcl[n] = fcv;
    l1l[n] = log2f(xe + 1e-10f);
    l2l[n] = log2f(1.0f - xe + 1e-10f);
    d3l[n][0] = 1.0f;
    d3l[n][1] = px * inv;
    d3l[n][2] = py * inv;
    d3l[n][3] = pz * inv;
  }
  __syncthreads();

  // FFE fill: all 256 threads (n = tid&63, band = tid>>6)
  {
    int n = tid & 63, band = tid >> 6;
    float fc_ = fcl[n] * d3l[n][band];
    float l1 = l1l[n], l2 = l2l[n];
    #pragma unroll
    for (int k = 0; k < NK; k++) {
      float v = exp2f(lb2l[k] + (float)k * l1 + (float)(24 - k) * l2) * fc_;
      FFE[(band * 32 + k) * 72 + n] = __float2bfloat16(v);
    }
  }
  __syncthreads();

  int lane = tid & 63, w = tid >> 6;
  int lr = lane & 15, lg = lane >> 4;

  f32x4 acc[8][2];
  #pragma unroll
  for (int mt = 0; mt < 8; mt++)
    #pragma unroll
    for (int nt = 0; nt < 2; nt++) acc[mt][nt] = (f32x4){0.f, 0.f, 0.f, 0.f};

  int f0 = 32 * w + lr, f1 = f0 + 16;
  #pragma unroll
  for (int s = 0; s < 2; s++) {
    bf16x8 b0, b1;
    #pragma unroll
    for (int j = 0; j < 8; j++) {
      int rb = jrow[s * 32 + lg * 8 + j];
      b0[j] = (short)yu[rb + f0];
      b1[j] = (short)yu[rb + f1];
    }
    #pragma unroll
    for (int mt = 0; mt < 8; mt++) {
      bf16x8 af = *(bf16x8*)((char*)FFE + (16 * mt + lr) * 144 + lg * 16 + s * 64);
      acc[mt][0] = __builtin_amdgcn_mfma_f32_16x16x32_bf16(af, b0, acc[mt][0], 0, 0, 0);
      acc[mt][1] = __builtin_amdgcn_mfma_f32_16x16x32_bf16(af, b1, acc[mt][1], 0, 0, 0);
    }
  }

  // epilogue: per-f contiguous weight rows WextT[f][band(2)][32]
  #pragma unroll
  for (int nt = 0; nt < 2; nt++) {
    int f = 32 * w + 16 * nt + lr;
    const float* wb = WextT + f * 64;
    float ps = 0.f, pp0 = 0.f, pp1 = 0.f, pp2 = 0.f;
    #pragma unroll
    for (int mt = 0; mt < 8; mt++) {
      float4 w4 = *(const float4*)&wb[(mt >> 1 ? 32 : 0) + 16 * (mt & 1) + 4 * lg];
      float t = w4.x * acc[mt][nt][0] + w4.y * acc[mt][nt][1]
              + w4.z * acc[mt][nt][2] + w4.w * acc[mt][nt][3];
      if      ((mt >> 1) == 0) ps  += t;
      else if ((mt >> 1) == 1) pp0 += t;
      else if ((mt >> 1) == 2) pp1 += t;
      else                     pp2 += t;
    }
    ps  += __shfl_xor(ps, 16);  ps  += __shfl_xor(ps, 32);
    pp0 += __shfl_xor(pp0, 16); pp0 += __shfl_xor(pp0, 32);
    pp1 += __shfl_xor(pp1, 16); pp1 += __shfl_xor(pp1, 32);
    pp2 += __shfl_xor(pp2, 16); pp2 += __shfl_xor(pp2, 32);
    if (lg == 0)
      cOut[atom * NF + f] = ps + pp0 * pp0 + pp1 * pp1 + pp2 * pp2;
  }
}

// ---------------- flash attention + residual: x += v + n ----------------
__global__ __launch_bounds__(256) void k_attn2(
    const __hip_bfloat16* __restrict__ Qw, const __hip_bfloat16* __restrict__ Kw,
    const __hip_bfloat16* __restrict__ Vw, const float* __restrict__ amask,
    const float* __restrict__ vres, float* __restrict__ x) {
  __shared__ __hip_bfloat16 Klds[64 * 136];
  __shared__ __hip_bfloat16 Vtlds[128 * 72];
  __shared__ __hip_bfloat16 Plds[4][16 * 72];
  int tid = threadIdx.x;
  int b = blockIdx.x >> 2;
  int q0 = (blockIdx.x & 3) * 64;
  int w = tid >> 6, l = tid & 63;
  int lr = l & 15, lg = l >> 4;
  int qbase = b * NA + q0 + w * 16;
  const float scale = 0.08838834764831845f;

  bf16x8 qf[4];
  #pragma unroll
  for (int ks = 0; ks < 4; ks++)
    qf[ks] = *(const bf16x8*)&Qw[(qbase + lr) * NF + ks * 32 + lg * 8];

  f32x4 O[8];
  #pragma unroll
  for (int nt = 0; nt < 8; nt++) O[nt] = (f32x4){0.f, 0.f, 0.f, 0.f};
  float mrun[4], srun[4];
  #pragma unroll
  for (int r = 0; r < 4; r++) { mrun[r] = -1e30f; srun[r] = 0.f; }

  for (int kc = 0; kc < 4; kc++) {
    #pragma unroll
    for (int it = 0; it < 4; it++) {
      int e = it * 256 + tid;
      int krow = e >> 4, f0 = (e & 15) * 8;
      *(bf16x8*)&Klds[krow * 136 + f0] = *(const bf16x8*)&Kw[(b * NA + kc * 64 + krow) * NF + f0];
      bf16x8 v8 = *(const bf16x8*)&Vw[(b * NA + kc * 64 + krow) * NF + f0];
      int vrot = (e & 7) * 8;
      int colv = (krow + vrot) & 63;
      #pragma unroll
      for (int j = 0; j < 8; j++)
        Vtlds[(f0 + j) * 72 + colv] = *((__hip_bfloat16*)&v8 + j);
    }
    __syncthreads();

    f32x4 sacc[4];
    #pragma unroll
    for (int ntc = 0; ntc < 4; ntc++) sacc[ntc] = (f32x4){0.f, 0.f, 0.f, 0.f};
    #pragma unroll
    for (int ks = 0; ks < 4; ks++)
      #pragma unroll
      for (int ntc = 0; ntc < 4; ntc++) {
        bf16x8 bfr = *(const bf16x8*)&Klds[(ntc * 16 + lr) * 136 + ks * 32 + lg * 8];
        sacc[ntc] = __builtin_amdgcn_mfma_f32_16x16x32_bf16(qf[ks], bfr, sacc[ntc], 0, 0, 0);
      }

    float kam[4];
    #pragma unroll
    for (int ntc = 0; ntc < 4; ntc++)
      kam[ntc] = (1.0f - amask[b * NA + kc * 64 + ntc * 16 + lr]) * (-1e9f);

    float plv[4][4];
    #pragma unroll
    for (int r = 0; r < 4; r++) {
      float lv[4];
      float cm = -1e30f;
      #pragma unroll
      for (int ntc = 0; ntc < 4; ntc++) {
        lv[ntc] = sacc[ntc][r] * scale + kam[ntc];
        cm = fmaxf(cm, lv[ntc]);
      }
      cm = fmaxf(cm, __shfl_xor(cm, 1)); cm = fmaxf(cm, __shfl_xor(cm, 2));
      cm = fmaxf(cm, __shfl_xor(cm, 4)); cm = fmaxf(cm, __shfl_xor(cm, 8));
      float mold = mrun[r];
      float mnew = fmaxf(mold, cm);
      float fr = expf(mold - mnew);
      float ps = 0.f;
      #pragma unroll
      for (int ntc = 0; ntc < 4; ntc++) {
        float p = expf(lv[ntc] - mnew);
        plv[ntc][r] = p;
        ps += p;
      }
      ps += __shfl_xor(ps, 1); ps += __shfl_xor(ps, 2);
      ps += __shfl_xor(ps, 4); ps += __shfl_xor(ps, 8);
      srun[r] = srun[r] * fr + ps;
      mrun[r] = mnew;
      #pragma unroll
      for (int nt = 0; nt < 8; nt++) O[nt][r] *= fr;
    }

    #pragma unroll
    for (int ntc = 0; ntc < 4; ntc++)
      #pragma unroll
      for (int r = 0; r < 4; r++)
        Plds[w][(4 * lg + r) * 72 + ntc * 16 + lr] = __float2bfloat16(plv[ntc][r]);
    bf16x8 pf[2];
    #pragma unroll
    for (int ki = 0; ki < 2; ki++)
      pf[ki] = *(const bf16x8*)&Plds[w][lr * 72 + ki * 32 + lg * 8];
    #pragma unroll
    for (int ki = 0; ki < 2; ki++)
      #pragma unroll
      for (int nt = 0; nt < 8; nt++) {
        int f = nt * 16 + lr;
        int rot = ((f >> 3) & 7) * 8;
        int n0 = (ki * 32 + lg * 8 + rot) & 63;
        bf16x8 bfr = *(const bf16x8*)&Vtlds[f * 72 + n0];
        O[nt] = __builtin_amdgcn_mfma_f32_16x16x32_bf16(pf[ki], bfr, O[nt], 0, 0, 0);
      }
    __syncthreads();
  }

  // x += v + n  (n = O/srun * amask_q)
  #pragma unroll
  for (int r = 0; r < 4; r++) {
    int q = qbase + 4 * lg + r;
    float inv = amask[q] / srun[r];
    #pragma unroll
    for (int nt = 0; nt < 8; nt++) {
      int f = nt * 16 + lr;
      x[q * NF + f] += vres[q * NF + f] + O[nt][r] * inv;
    }
  }
}

// ---------------- host launch ----------------
extern "C" void kernel_launch(void* const* d_in, const int* in_sizes, int n_in,
                              void* d_out, int out_size, void* d_ws, size_t ws_size,
                              hipStream_t stream) {
  const float* pos   = (const float*)d_in[0];
  const float* nmask = (const float*)d_in[1];
  const float* amask = (const float*)d_in[2];
  const float* emb   = (const float*)d_in[3];
  const float* Wfs   = (const float*)d_in[4];
  const float* Wfp   = (const float*)d_in[5];
  const float* Win   = (const float*)d_in[6];
  const float* Wf2o  = (const float*)d_in[7];
  const float* bf2o  = (const float*)d_in[8];
  const float* Wd    = (const float*)d_in[9];
  const float* bd    = (const float*)d_in[10];
  const float* Wq    = (const float*)d_in[11];
  const float* Wk    = (const float*)d_in[12];
  const float* Wv    = (const float*)d_in[13];
  const int*   Z     = (const int*)d_in[14];
  const int*   nbrs  = (const int*)d_in[15];

  float* x = (float*)d_out;
  float* wsf = (float*)d_ws;
  const int S = NATOM * NF;                 // 524288
  float* Cb  = wsf;                                         // f32
  float* Vb  = wsf + S;                                     // f32
  __hip_bfloat16* ybf = (__hip_bfloat16*)(wsf + 2 * S);
  __hip_bfloat16* Qw  = ybf + S;
  __hip_bfloat16* Kw  = ybf + 2 * S;
  __hip_bfloat16* Vw  = ybf + 3 * S;
  __hip_bfloat16* WT  = ybf + 4 * S;                        // 18*16384 bf16
  float* WextT = (float*)(WT + 18 * 16384);                 // 24576 f32

  k_prep<<<dim3(1152), dim3(256), 0, stream>>>(Win, Wf2o, Wd, Wq, Wk, Wv, WT);
  k_wextT<<<dim3(96), dim3(256), 0, stream>>>(Wfs, Wfp, WextT);
  k_embed<<<dim3(NATOM * NF / 256), dim3(256), 0, stream>>>(Z, emb, x);

  for (int l = 0; l < 3; l++) {
    const __hip_bfloat16* WTl = WT + l * 6 * 16384;
    const float* WextT_l = WextT + l * NF * 64;

    // y, q, k, v projections (one dispatch)
    k_proj<<<dim3(256, 4), dim3(64), 0, stream>>>(x, amask, WTl, ybf, Qw, Kw, Vw);
    // c = cs + cp (per-atom MFMA, direct-global B-frags)
    k_filter_mfma<<<dim3(NATOM), dim3(256), 0, stream>>>(ybf, nbrs, pos, nmask, WextT_l, Cb);
    // h = ssp(c@Wf2o+b); v = h@Wd+b (fused)
    k_hv<<<dim3(256), dim3(64), 0, stream>>>(Cb, WTl + 16384, bf2o + l * NF,
                                             WTl + 2 * 16384, bd + l * NF, Vb);
    // flash attention + residual: x += v + n
    k_attn2<<<dim3(NB * 4), dim3(256), 0, stream>>>(Qw, Kw, Vw, amask, Vb, x);
  }
}

// Round 6
// 239.451 us; speedup vs baseline: 2.4393x; 1.2057x over previous
//
#include <hip/hip_runtime.h>
#include <hip/hip_bf16.h>
#include <math.h>

// TbpNet: B=16, A=256, NBH=64, F=128, K=25, L=3.
// R5: filter Ws-formulation (64 MFMAs, weight B-operands, coalesced yj LDS);
//     hv fused into attention epilogue; single init dispatch.
#define NB   16
#define NA   256
#define NNBH 64
#define NF   128
#define NK   25
#define NATOM (NB*NA)   // 4096

typedef __attribute__((ext_vector_type(4))) float f32x4;
typedef __attribute__((ext_vector_type(8))) short bf16x8;

__device__ __constant__ float BINOM_C[25] = {
  1.f, 24.f, 276.f, 2024.f, 10626.f, 42504.f, 134596.f, 346104.f,
  735471.f, 1307504.f, 1961256.f, 2496144.f, 2704156.f, 2496144.f,
  1961256.f, 1307504.f, 735471.f, 346104.f, 134596.f, 42504.f,
  10626.f, 2024.f, 276.f, 24.f, 1.f
};

__device__ __forceinline__ float sspf(float x) {
  float t = (x > 20.f) ? x : log1pf(expf(x));
  return t - 0.69314718055994531f;
}
__device__ __forceinline__ unsigned short f2bf(float x) {
  __hip_bfloat16 h = __float2bfloat16(x);
  return *(unsigned short*)&h;
}

// ---------------- init: embed + WT prep + Wfb prep (one dispatch) ----------------
__global__ __launch_bounds__(256) void k_init(
    const int* __restrict__ Z, const float* __restrict__ emb,
    const float* __restrict__ Win, const float* __restrict__ Wf2o,
    const float* __restrict__ Wd, const float* __restrict__ Wq,
    const float* __restrict__ Wk, const float* __restrict__ Wv,
    const float* __restrict__ Wfs, const float* __restrict__ Wfp,
    float* __restrict__ x, __hip_bfloat16* __restrict__ WT,
    __hip_bfloat16* __restrict__ Wfb) {
  int bid = blockIdx.x, tid = threadIdx.x;
  if (bid < 2048) {
    int i = bid * 256 + tid;
    x[i] = emb[Z[i >> 7] * NF + (i & 127)];
  } else if (bid < 3200) {
    int idx = (bid - 2048) * 256 + tid;      // 18*16384
    int e = idx & 16383; int m = idx >> 14;
    int l = m / 6, wsel = m - l * 6;
    const float* src = (wsel == 0) ? Win : (wsel == 1) ? Wf2o : (wsel == 2) ? Wd
                      : (wsel == 3) ? Wq : (wsel == 4) ? Wk : Wv;
    int k = e >> 7, col = e & 127;
    WT[m * 16384 + col * 128 + k] = __float2bfloat16(src[l * NF * NF + k * NF + col]);
  } else {
    int idx = (bid - 3200) * 256 + tid;      // 3*2*128*32 = 24576
    int k = idx & 31, f = (idx >> 5) & 127, s = (idx >> 12) & 1, l = idx >> 13;
    float v = 0.f;
    if (k < NK) v = (s ? Wfp : Wfs)[l * NK * NF + k * NF + f];
    Wfb[idx] = __float2bfloat16(v);          // [l][s][f][k]
  }
}

// ---------------- fused projections: z=0 y, z=1 q, z=2 k, z=3 v ----------------
__global__ __launch_bounds__(64) void k_proj(
    const float* __restrict__ x, const float* __restrict__ amask,
    const __hip_bfloat16* __restrict__ WTl,
    __hip_bfloat16* __restrict__ ybf, __hip_bfloat16* __restrict__ Qw,
    __hip_bfloat16* __restrict__ Kw, __hip_bfloat16* __restrict__ Vw) {
  int z = blockIdx.y;
  const __hip_bfloat16* WT = WTl + ((z == 0) ? 0 : (z + 2)) * (NF * NF);
  __hip_bfloat16* out = (z == 0) ? ybf : (z == 1) ? Qw : (z == 2) ? Kw : Vw;
  int l = threadIdx.x, lr = l & 15, lg = l >> 4;
  int row = blockIdx.x * 16 + lr;
  float am = (z > 0) ? amask[row] : 1.0f;
  const float* xr = x + row * NF;

  bf16x8 afr[4];
  #pragma unroll
  for (int ks = 0; ks < 4; ks++) {
    int k0 = ks * 32 + lg * 8;
    float4 a = *(const float4*)&xr[k0];
    float4 c = *(const float4*)&xr[k0 + 4];
    bf16x8 t;
    t[0] = (short)f2bf(a.x * am); t[1] = (short)f2bf(a.y * am);
    t[2] = (short)f2bf(a.z * am); t[3] = (short)f2bf(a.w * am);
    t[4] = (short)f2bf(c.x * am); t[5] = (short)f2bf(c.y * am);
    t[6] = (short)f2bf(c.z * am); t[7] = (short)f2bf(c.w * am);
    afr[ks] = t;
  }

  f32x4 acc[8];
  #pragma unroll
  for (int nt = 0; nt < 8; nt++) acc[nt] = (f32x4){0.f, 0.f, 0.f, 0.f};
  #pragma unroll
  for (int ks = 0; ks < 4; ks++)
    #pragma unroll
    for (int nt = 0; nt < 8; nt++) {
      bf16x8 bfr = *(const bf16x8*)(WT + (nt * 16 + lr) * NF + ks * 32 + lg * 8);
      acc[nt] = __builtin_amdgcn_mfma_f32_16x16x32_bf16(afr[ks], bfr, acc[nt], 0, 0, 0);
    }

  #pragma unroll
  for (int nt = 0; nt < 8; nt++) {
    int col = nt * 16 + lr;
    #pragma unroll
    for (int r = 0; r < 4; r++) {
      int orow = blockIdx.x * 16 + lg * 4 + r;
      float o = acc[nt][r];
      if (z > 0) o = sspf(o);
      out[orow * NF + col] = __float2bfloat16(o);
    }
  }
}

// ---------------- MFMA filter v3 (per atom): Ws = FF@Wfs, Wp = FF@Wfp ----------------
// cs[f] = sum_n yj[n][f]*Ws[n][f];  cp = sum_m (sum_n d_m[n]*yj[n][f]*Wp[n][f])^2
__global__ __launch_bounds__(256) void k_filter_mfma(
    const __hip_bfloat16* __restrict__ ybf, const int* __restrict__ nbrs,
    const float* __restrict__ pos, const float* __restrict__ nmask,
    const __hip_bfloat16* __restrict__ Wfb_l, float* __restrict__ cOut) {
  __shared__ __hip_bfloat16 FF[64 * 40];     // [n][k], stride 40 (80 B)
  __shared__ __hip_bfloat16 yjl[64 * 132];   // [n][f], stride 132 (264 B)
  __shared__ float d3l[64][4];
  __shared__ float fcl[64], l1l[64], l2l[64];
  __shared__ int jl[64];
  __shared__ float lb2l[32];
  int tid = threadIdx.x, atom = blockIdx.x, brow = atom & ~(NA - 1);

  if (tid >= 64 && tid < 64 + NK) lb2l[tid - 64] = log2f(BINOM_C[tid - 64]);
  if (tid < NNBH) {
    int n = tid;
    int j = nbrs[atom * NNBH + n];
    jl[n] = j;
    float px = pos[(brow + j) * 3 + 0] - pos[atom * 3 + 0];
    float py = pos[(brow + j) * 3 + 1] - pos[atom * 3 + 1];
    float pz = pos[(brow + j) * 3 + 2] - pos[atom * 3 + 2];
    float m = nmask[atom * NNBH + n];
    float r = sqrtf(px * px + py * py + pz * pz + 1e-12f) * m;
    float inv = 1.0f / (r + 1e-9f);
    float fcv = (r < 5.0f) ? (0.5f * cosf(0.62831853071795865f * r) + 0.5f) * m : 0.0f;
    float xe = expf(-r);
    fcl[n] = fcv;
    l1l[n] = log2f(xe + 1e-10f);
    l2l[n] = log2f(1.0f - xe + 1e-10f);
    d3l[n][0] = 0.f;
    d3l[n][1] = px * inv;
    d3l[n][2] = py * inv;
    d3l[n][3] = pz * inv;
  }
  __syncthreads();

  // FF fill: thread (n = tid&63, kq = tid>>6) does k = kq*8..kq*8+7 (one 16B write)
  {
    int n = tid & 63, kq = tid >> 6;
    float l1 = l1l[n], l2 = l2l[n], fc = fcl[n];
    bf16x8 v;
    #pragma unroll
    for (int j = 0; j < 8; j++) {
      int k = kq * 8 + j;
      float val = 0.f;
      if (k < NK) val = exp2f(lb2l[k] + (float)k * l1 + (float)(24 - k) * l2) * fc;
      v[j] = (short)f2bf(val);
    }
    *(bf16x8*)&FF[n * 40 + kq * 8] = v;
  }
  // yjl stage: coalesced row loads, linear LDS writes (no transpose needed)
  {
    int n = tid >> 2, c0 = (tid & 3) * 32;
    const __hip_bfloat16* src = &ybf[(brow + jl[n]) * NF + c0];
    #pragma unroll
    for (int i = 0; i < 4; i++) {
      uint4 u = *(const uint4*)(src + i * 8);
      uint2* dst = (uint2*)&yjl[n * 132 + c0 + i * 8];
      dst[0] = make_uint2(u.x, u.y);
      dst[1] = make_uint2(u.z, u.w);
    }
  }
  __syncthreads();

  int lane = tid & 63, w = tid >> 6, lr = lane & 15, lg = lane >> 4;

  // A-frags: all 4 m-tiles (n-rows); wave owns f-columns 32w..32w+31
  bf16x8 af[4];
  #pragma unroll
  for (int mt = 0; mt < 4; mt++)
    af[mt] = *(bf16x8*)&FF[(16 * mt + lr) * 40 + lg * 8];

  f32x4 as_[4][2], ap_[4][2];
  #pragma unroll
  for (int mt = 0; mt < 4; mt++)
    #pragma unroll
    for (int nt2 = 0; nt2 < 2; nt2++) {
      as_[mt][nt2] = (f32x4){0.f, 0.f, 0.f, 0.f};
      ap_[mt][nt2] = (f32x4){0.f, 0.f, 0.f, 0.f};
    }
  #pragma unroll
  for (int nt2 = 0; nt2 < 2; nt2++) {
    int col = 32 * w + 16 * nt2 + lr;
    bf16x8 bs = *(const bf16x8*)&Wfb_l[col * 32 + lg * 8];
    bf16x8 bp = *(const bf16x8*)&Wfb_l[(128 + col) * 32 + lg * 8];
    #pragma unroll
    for (int mt = 0; mt < 4; mt++) {
      as_[mt][nt2] = __builtin_amdgcn_mfma_f32_16x16x32_bf16(af[mt], bs, as_[mt][nt2], 0, 0, 0);
      ap_[mt][nt2] = __builtin_amdgcn_mfma_f32_16x16x32_bf16(af[mt], bp, ap_[mt][nt2], 0, 0, 0);
    }
  }

  // neighbor contraction (VALU): lane covers n = 16mt+4lg+r, f = 32w+16nt2+lr
  float qs[2] = {0.f, 0.f}, q1[2] = {0.f, 0.f}, q2[2] = {0.f, 0.f}, q3[2] = {0.f, 0.f};
  #pragma unroll
  for (int mt = 0; mt < 4; mt++) {
    #pragma unroll
    for (int r = 0; r < 4; r++) {
      int n = 16 * mt + 4 * lg + r;
      float4 dv = *(const float4*)&d3l[n][0];
      #pragma unroll
      for (int nt2 = 0; nt2 < 2; nt2++) {
        int f = 32 * w + 16 * nt2 + lr;
        float yv = __bfloat162float(yjl[n * 132 + f]);
        qs[nt2] += yv * as_[mt][nt2][r];
        float pw = yv * ap_[mt][nt2][r];
        q1[nt2] += dv.y * pw;
        q2[nt2] += dv.z * pw;
        q3[nt2] += dv.w * pw;
      }
    }
  }
  #pragma unroll
  for (int nt2 = 0; nt2 < 2; nt2++) {
    float a = qs[nt2], b1 = q1[nt2], b2 = q2[nt2], b3 = q3[nt2];
    a  += __shfl_xor(a, 16);  a  += __shfl_xor(a, 32);
    b1 += __shfl_xor(b1, 16); b1 += __shfl_xor(b1, 32);
    b2 += __shfl_xor(b2, 16); b2 += __shfl_xor(b2, 32);
    b3 += __shfl_xor(b3, 16); b3 += __shfl_xor(b3, 32);
    if (lg == 0)
      cOut[atom * NF + 32 * w + 16 * nt2 + lr] = a + b1 * b1 + b2 * b2 + b3 * b3;
  }
}

// ---------------- flash attention + fused hv + residual: x += v + n ----------------
__global__ __launch_bounds__(256) void k_attn2(
    const __hip_bfloat16* __restrict__ Qw, const __hip_bfloat16* __restrict__ Kw,
    const __hip_bfloat16* __restrict__ Vw, const float* __restrict__ amask,
    const float* __restrict__ Cb, const __hip_bfloat16* __restrict__ WTf2o,
    const float* __restrict__ bf2o_l, const __hip_bfloat16* __restrict__ WTd,
    const float* __restrict__ bd_l, float* __restrict__ x) {
  __shared__ __hip_bfloat16 Klds[64 * 136];
  __shared__ __hip_bfloat16 Vtlds[128 * 72];
  __shared__ __hip_bfloat16 Plds[4][16 * 72];
  int tid = threadIdx.x;
  int b = blockIdx.x >> 2;
  int q0 = (blockIdx.x & 3) * 64;
  int w = tid >> 6, l = tid & 63;
  int lr = l & 15, lg = l >> 4;
  int qbase = b * NA + q0 + w * 16;
  const float scale = 0.08838834764831845f;

  bf16x8 qf[4];
  #pragma unroll
  for (int ks = 0; ks < 4; ks++)
    qf[ks] = *(const bf16x8*)&Qw[(qbase + lr) * NF + ks * 32 + lg * 8];

  f32x4 O[8];
  #pragma unroll
  for (int nt = 0; nt < 8; nt++) O[nt] = (f32x4){0.f, 0.f, 0.f, 0.f};
  float mrun[4], srun[4];
  #pragma unroll
  for (int r = 0; r < 4; r++) { mrun[r] = -1e30f; srun[r] = 0.f; }

  for (int kc = 0; kc < 4; kc++) {
    #pragma unroll
    for (int it = 0; it < 4; it++) {
      int e = it * 256 + tid;
      int krow = e >> 4, f0 = (e & 15) * 8;
      *(bf16x8*)&Klds[krow * 136 + f0] = *(const bf16x8*)&Kw[(b * NA + kc * 64 + krow) * NF + f0];
      bf16x8 v8 = *(const bf16x8*)&Vw[(b * NA + kc * 64 + krow) * NF + f0];
      int vrot = (e & 7) * 8;
      int colv = (krow + vrot) & 63;
      #pragma unroll
      for (int j = 0; j < 8; j++)
        Vtlds[(f0 + j) * 72 + colv] = *((__hip_bfloat16*)&v8 + j);
    }
    __syncthreads();

    f32x4 sacc[4];
    #pragma unroll
    for (int ntc = 0; ntc < 4; ntc++) sacc[ntc] = (f32x4){0.f, 0.f, 0.f, 0.f};
    #pragma unroll
    for (int ks = 0; ks < 4; ks++)
      #pragma unroll
      for (int ntc = 0; ntc < 4; ntc++) {
        bf16x8 bfr = *(const bf16x8*)&Klds[(ntc * 16 + lr) * 136 + ks * 32 + lg * 8];
        sacc[ntc] = __builtin_amdgcn_mfma_f32_16x16x32_bf16(qf[ks], bfr, sacc[ntc], 0, 0, 0);
      }

    float kam[4];
    #pragma unroll
    for (int ntc = 0; ntc < 4; ntc++)
      kam[ntc] = (1.0f - amask[b * NA + kc * 64 + ntc * 16 + lr]) * (-1e9f);

    float plv[4][4];
    #pragma unroll
    for (int r = 0; r < 4; r++) {
      float lv[4];
      float cm = -1e30f;
      #pragma unroll
      for (int ntc = 0; ntc < 4; ntc++) {
        lv[ntc] = sacc[ntc][r] * scale + kam[ntc];
        cm = fmaxf(cm, lv[ntc]);
      }
      cm = fmaxf(cm, __shfl_xor(cm, 1)); cm = fmaxf(cm, __shfl_xor(cm, 2));
      cm = fmaxf(cm, __shfl_xor(cm, 4)); cm = fmaxf(cm, __shfl_xor(cm, 8));
      float mold = mrun[r];
      float mnew = fmaxf(mold, cm);
      float fr = expf(mold - mnew);
      float ps = 0.f;
      #pragma unroll
      for (int ntc = 0; ntc < 4; ntc++) {
        float p = expf(lv[ntc] - mnew);
        plv[ntc][r] = p;
        ps += p;
      }
      ps += __shfl_xor(ps, 1); ps += __shfl_xor(ps, 2);
      ps += __shfl_xor(ps, 4); ps += __shfl_xor(ps, 8);
      srun[r] = srun[r] * fr + ps;
      mrun[r] = mnew;
      #pragma unroll
      for (int nt = 0; nt < 8; nt++) O[nt][r] *= fr;
    }

    #pragma unroll
    for (int ntc = 0; ntc < 4; ntc++)
      #pragma unroll
      for (int r = 0; r < 4; r++)
        Plds[w][(4 * lg + r) * 72 + ntc * 16 + lr] = __float2bfloat16(plv[ntc][r]);
    bf16x8 pf[2];
    #pragma unroll
    for (int ki = 0; ki < 2; ki++)
      pf[ki] = *(const bf16x8*)&Plds[w][lr * 72 + ki * 32 + lg * 8];
    #pragma unroll
    for (int ki = 0; ki < 2; ki++)
      #pragma unroll
      for (int nt = 0; nt < 8; nt++) {
        int f = nt * 16 + lr;
        int rot = ((f >> 3) & 7) * 8;
        int n0 = (ki * 32 + lg * 8 + rot) & 63;
        bf16x8 bfr = *(const bf16x8*)&Vtlds[f * 72 + n0];
        O[nt] = __builtin_amdgcn_mfma_f32_16x16x32_bf16(pf[ki], bfr, O[nt], 0, 0, 0);
      }
    __syncthreads();
  }

  // ---- fused hv: h = ssp(c@Wf2o+b); v = h@Wd+b (wave's 16 rows) ----
  __hip_bfloat16* Hs = &Klds[w * 16 * 136];   // alias (flash done with Klds)
  {
    int rowg = qbase + lr;
    bf16x8 cfr[4];
    #pragma unroll
    for (int ks = 0; ks < 4; ks++) {
      int k0 = ks * 32 + lg * 8;
      float4 a = *(const float4*)&Cb[rowg * NF + k0];
      float4 c = *(const float4*)&Cb[rowg * NF + k0 + 4];
      bf16x8 t;
      t[0] = (short)f2bf(a.x); t[1] = (short)f2bf(a.y);
      t[2] = (short)f2bf(a.z); t[3] = (short)f2bf(a.w);
      t[4] = (short)f2bf(c.x); t[5] = (short)f2bf(c.y);
      t[6] = (short)f2bf(c.z); t[7] = (short)f2bf(c.w);
      cfr[ks] = t;
    }
    f32x4 hacc[8];
    #pragma unroll
    for (int nt = 0; nt < 8; nt++) hacc[nt] = (f32x4){0.f, 0.f, 0.f, 0.f};
    #pragma unroll
    for (int ks = 0; ks < 4; ks++)
      #pragma unroll
      for (int nt = 0; nt < 8; nt++) {
        bf16x8 bfr = *(const bf16x8*)(WTf2o + (nt * 16 + lr) * NF + ks * 32 + lg * 8);
        hacc[nt] = __builtin_amdgcn_mfma_f32_16x16x32_bf16(cfr[ks], bfr, hacc[nt], 0, 0, 0);
      }
    #pragma unroll
    for (int nt = 0; nt < 8; nt++) {
      int col = nt * 16 + lr;
      float bv = bf2o_l[col];
      #pragma unroll
      for (int r = 0; r < 4; r++)
        Hs[(4 * lg + r) * 136 + col] = __float2bfloat16(sspf(hacc[nt][r] + bv));
    }
  }
  __syncthreads();
  {
    bf16x8 hfr[4];
    #pragma unroll
    for (int ks = 0; ks < 4; ks++)
      hfr[ks] = *(const bf16x8*)&Hs[lr * 136 + ks * 32 + lg * 8];
    f32x4 vacc[8];
    #pragma unroll
    for (int nt = 0; nt < 8; nt++) vacc[nt] = (f32x4){0.f, 0.f, 0.f, 0.f};
    #pragma unroll
    for (int ks = 0; ks < 4; ks++)
      #pragma unroll
      for (int nt = 0; nt < 8; nt++) {
        bf16x8 bfr = *(const bf16x8*)(WTd + (nt * 16 + lr) * NF + ks * 32 + lg * 8);
        vacc[nt] = __builtin_amdgcn_mfma_f32_16x16x32_bf16(hfr[ks], bfr, vacc[nt], 0, 0, 0);
      }
    // x += v + n  (n = O/srun * amask_q) — vacc and O share C-layout
    #pragma unroll
    for (int r = 0; r < 4; r++) {
      int q = qbase + 4 * lg + r;
      float inv = amask[q] / srun[r];
      #pragma unroll
      for (int nt = 0; nt < 8; nt++) {
        int f = nt * 16 + lr;
        x[q * NF + f] += vacc[nt][r] + bd_l[f] + O[nt][r] * inv;
      }
    }
  }
}

// ---------------- host launch ----------------
extern "C" void kernel_launch(void* const* d_in, const int* in_sizes, int n_in,
                              void* d_out, int out_size, void* d_ws, size_t ws_size,
                              hipStream_t stream) {
  const float* pos   = (const float*)d_in[0];
  const float* nmask = (const float*)d_in[1];
  const float* amask = (const float*)d_in[2];
  const float* emb   = (const float*)d_in[3];
  const float* Wfs   = (const float*)d_in[4];
  const float* Wfp   = (const float*)d_in[5];
  const float* Win   = (const float*)d_in[6];
  const float* Wf2o  = (const float*)d_in[7];
  const float* bf2o  = (const float*)d_in[8];
  const float* Wd    = (const float*)d_in[9];
  const float* bd    = (const float*)d_in[10];
  const float* Wq    = (const float*)d_in[11];
  const float* Wk    = (const float*)d_in[12];
  const float* Wv    = (const float*)d_in[13];
  const int*   Z     = (const int*)d_in[14];
  const int*   nbrs  = (const int*)d_in[15];

  float* x = (float*)d_out;
  float* wsf = (float*)d_ws;
  const int S = NATOM * NF;                               // 524288
  float* Cb = wsf;                                        // S f32
  __hip_bfloat16* ybf = (__hip_bfloat16*)(wsf + S);
  __hip_bfloat16* Qw  = ybf + S;
  __hip_bfloat16* Kw  = Qw + S;
  __hip_bfloat16* Vw  = Kw + S;
  __hip_bfloat16* WT  = Vw + S;                           // 18*16384 bf16
  __hip_bfloat16* Wfb = WT + 18 * 16384;                  // 24576 bf16

  k_init<<<dim3(3296), dim3(256), 0, stream>>>(
      Z, emb, Win, Wf2o, Wd, Wq, Wk, Wv, Wfs, Wfp, x, WT, Wfb);

  for (int l = 0; l < 3; l++) {
    const __hip_bfloat16* WTl = WT + l * 6 * 16384;

    // y, q, k, v projections
    k_proj<<<dim3(256, 4), dim3(64), 0, stream>>>(x, amask, WTl, ybf, Qw, Kw, Vw);
    // filter: c = cs + cp
    k_filter_mfma<<<dim3(NATOM), dim3(256), 0, stream>>>(
        ybf, nbrs, pos, nmask, Wfb + l * 8192, Cb);
    // flash attention + hv + residual: x += v + n
    k_attn2<<<dim3(NB * 4), dim3(256), 0, stream>>>(
        Qw, Kw, Vw, amask, Cb, WTl + 16384, bf2o + l * NF,
        WTl + 2 * 16384, bd + l * NF, x);
  }
}

// Round 8
// 206.116 us; speedup vs baseline: 2.8338x; 1.1617x over previous
//
#include <hip/hip_runtime.h>
#include <hip/hip_bf16.h>
#include <math.h>

// TbpNet: B=16, A=256, NBH=64, F=128, K=25, L=3.
// R7: R6 + fix hLDS stride collision (68 -> 132) + revert __expf -> expf.
#define NB   16
#define NA   256
#define NNBH 64
#define NF   128
#define NK   25
#define NATOM (NB*NA)   // 4096

typedef __attribute__((ext_vector_type(4))) float f32x4;
typedef __attribute__((ext_vector_type(8))) short bf16x8;

__device__ __constant__ float BINOM_C[25] = {
  1.f, 24.f, 276.f, 2024.f, 10626.f, 42504.f, 134596.f, 346104.f,
  735471.f, 1307504.f, 1961256.f, 2496144.f, 2704156.f, 2496144.f,
  1961256.f, 1307504.f, 735471.f, 346104.f, 134596.f, 42504.f,
  10626.f, 2024.f, 276.f, 24.f, 1.f
};

__device__ __forceinline__ float sspf(float x) {
  float t = (x > 20.f) ? x : log1pf(expf(x));
  return t - 0.69314718055994531f;
}
__device__ __forceinline__ unsigned short f2bf(float x) {
  __hip_bfloat16 h = __float2bfloat16(x);
  return *(unsigned short*)&h;
}

// ---------------- init: embed + WT prep + Wfb prep ----------------
__global__ __launch_bounds__(256) void k_init(
    const int* __restrict__ Z, const float* __restrict__ emb,
    const float* __restrict__ Win, const float* __restrict__ Wf2o,
    const float* __restrict__ Wd, const float* __restrict__ Wq,
    const float* __restrict__ Wk, const float* __restrict__ Wv,
    const float* __restrict__ Wfs, const float* __restrict__ Wfp,
    float* __restrict__ x, __hip_bfloat16* __restrict__ WT,
    __hip_bfloat16* __restrict__ Wfb) {
  int bid = blockIdx.x, tid = threadIdx.x;
  if (bid < 2048) {
    int i = bid * 256 + tid;
    x[i] = emb[Z[i >> 7] * NF + (i & 127)];
  } else if (bid < 3200) {
    int idx = (bid - 2048) * 256 + tid;      // 18*16384
    int e = idx & 16383; int m = idx >> 14;
    int l = m / 6, wsel = m - l * 6;
    const float* src = (wsel == 0) ? Win : (wsel == 1) ? Wf2o : (wsel == 2) ? Wd
                      : (wsel == 3) ? Wq : (wsel == 4) ? Wk : Wv;
    int k = e >> 7, col = e & 127;
    WT[m * 16384 + col * 128 + k] = __float2bfloat16(src[l * NF * NF + k * NF + col]);
  } else {
    int idx = (bid - 3200) * 256 + tid;      // 3*2*128*32 = 24576
    int k = idx & 31, f = (idx >> 5) & 127, s = (idx >> 12) & 1, l = idx >> 13;
    float v = 0.f;
    if (k < NK) v = (s ? Wfp : Wfs)[l * NK * NF + k * NF + f];
    Wfb[idx] = __float2bfloat16(v);          // [l][s][f][k]
  }
}

// ---------------- projections: wave z: 0->y, 1->q, 2->k, 3->v(T) ----------------
__global__ __launch_bounds__(256) void k_proj(
    const float* __restrict__ x, const float* __restrict__ amask,
    const __hip_bfloat16* __restrict__ WTl,
    __hip_bfloat16* __restrict__ ybf, __hip_bfloat16* __restrict__ Qw,
    __hip_bfloat16* __restrict__ Kw, __hip_bfloat16* __restrict__ VwT) {
  int tid = threadIdx.x;
  int z = tid >> 6, l = tid & 63, lr = l & 15, lg = l >> 4;
  const __hip_bfloat16* WT = WTl + ((z == 0) ? 0 : (z + 2)) * (NF * NF);
  int row = blockIdx.x * 16 + lr;
  float am = (z > 0) ? amask[row] : 1.0f;
  const float* xr = x + row * NF;

  bf16x8 afr[4];
  #pragma unroll
  for (int ks = 0; ks < 4; ks++) {
    int k0 = ks * 32 + lg * 8;
    float4 a = *(const float4*)&xr[k0];
    float4 c = *(const float4*)&xr[k0 + 4];
    bf16x8 t;
    t[0] = (short)f2bf(a.x * am); t[1] = (short)f2bf(a.y * am);
    t[2] = (short)f2bf(a.z * am); t[3] = (short)f2bf(a.w * am);
    t[4] = (short)f2bf(c.x * am); t[5] = (short)f2bf(c.y * am);
    t[6] = (short)f2bf(c.z * am); t[7] = (short)f2bf(c.w * am);
    afr[ks] = t;
  }

  f32x4 acc[8];
  #pragma unroll
  for (int nt = 0; nt < 8; nt++) acc[nt] = (f32x4){0.f, 0.f, 0.f, 0.f};
  #pragma unroll
  for (int ks = 0; ks < 4; ks++)
    #pragma unroll
    for (int nt = 0; nt < 8; nt++) {
      bf16x8 bfr = *(const bf16x8*)(WT + (nt * 16 + lr) * NF + ks * 32 + lg * 8);
      acc[nt] = __builtin_amdgcn_mfma_f32_16x16x32_bf16(afr[ks], bfr, acc[nt], 0, 0, 0);
    }

  if (z < 3) {
    __hip_bfloat16* out = (z == 0) ? ybf : (z == 1) ? Qw : Kw;
    #pragma unroll
    for (int nt = 0; nt < 8; nt++) {
      int col = nt * 16 + lr;
      #pragma unroll
      for (int r = 0; r < 4; r++) {
        int orow = blockIdx.x * 16 + lg * 4 + r;
        float o = acc[nt][r];
        if (z > 0) o = sspf(o);
        out[orow * NF + col] = __float2bfloat16(o);
      }
    }
  } else {
    int b = blockIdx.x >> 4;
    int ar0 = (blockIdx.x & 15) * 16 + lg * 4;
    #pragma unroll
    for (int nt = 0; nt < 8; nt++) {
      int col = nt * 16 + lr;
      #pragma unroll
      for (int r = 0; r < 4; r++)
        VwT[(b * NF + col) * NA + ar0 + r] = __float2bfloat16(sspf(acc[nt][r]));
    }
  }
}

// ---------------- MFMA filter (per atom) ----------------
__global__ __launch_bounds__(256) void k_filter_mfma(
    const __hip_bfloat16* __restrict__ ybf, const int* __restrict__ nbrs,
    const float* __restrict__ pos, const float* __restrict__ nmask,
    const __hip_bfloat16* __restrict__ Wfb_l, float* __restrict__ cOut) {
  __shared__ __hip_bfloat16 FF[64 * 40];     // [n][k], stride 40
  __shared__ __hip_bfloat16 yjl[64 * 132];   // [n][f], stride 132
  __shared__ float d3l[64][4];
  __shared__ int jl[64];
  int tid = threadIdx.x, atom = blockIdx.x, brow = atom & ~(NA - 1);

  // geometry: all threads, n = tid&63 (redundant x4, L1-cached loads)
  {
    int n = tid & 63;
    int j = nbrs[atom * NNBH + n];
    float px = pos[(brow + j) * 3 + 0] - pos[atom * 3 + 0];
    float py = pos[(brow + j) * 3 + 1] - pos[atom * 3 + 1];
    float pz = pos[(brow + j) * 3 + 2] - pos[atom * 3 + 2];
    float m = nmask[atom * NNBH + n];
    float r = sqrtf(px * px + py * py + pz * pz + 1e-12f) * m;
    float inv = 1.0f / (r + 1e-9f);
    float fc = (r < 5.0f) ? (0.5f * cosf(0.62831853071795865f * r) + 0.5f) * m : 0.0f;
    float xe = expf(-r);
    float l1 = log2f(xe + 1e-10f);
    float l2 = log2f(1.0f - xe + 1e-10f);
    if (tid < NNBH) {
      jl[n] = j;
      d3l[n][0] = 0.f;
      d3l[n][1] = px * inv;
      d3l[n][2] = py * inv;
      d3l[n][3] = pz * inv;
    }
    // FF fill: (n, kq = tid>>6), k = kq*8..kq*8+7
    int kq = tid >> 6;
    bf16x8 v;
    #pragma unroll
    for (int j8 = 0; j8 < 8; j8++) {
      int k = kq * 8 + j8;
      float val = 0.f;
      if (k < NK)
        val = BINOM_C[k] * exp2f((float)k * l1 + (float)(24 - k) * l2) * fc;
      v[j8] = (short)f2bf(val);
    }
    *(bf16x8*)&FF[n * 40 + kq * 8] = v;
  }
  __syncthreads();

  // yjl stage: coalesced row loads, linear LDS writes
  {
    int n = tid >> 2, c0 = (tid & 3) * 32;
    const __hip_bfloat16* src = &ybf[(brow + jl[n]) * NF + c0];
    #pragma unroll
    for (int i = 0; i < 4; i++) {
      uint4 u = *(const uint4*)(src + i * 8);
      uint2* dst = (uint2*)&yjl[n * 132 + c0 + i * 8];
      dst[0] = make_uint2(u.x, u.y);
      dst[1] = make_uint2(u.z, u.w);
    }
  }
  __syncthreads();

  int lane = tid & 63, w = tid >> 6, lr = lane & 15, lg = lane >> 4;

  bf16x8 af[4];
  #pragma unroll
  for (int mt = 0; mt < 4; mt++)
    af[mt] = *(bf16x8*)&FF[(16 * mt + lr) * 40 + lg * 8];

  f32x4 as_[4][2], ap_[4][2];
  #pragma unroll
  for (int mt = 0; mt < 4; mt++)
    #pragma unroll
    for (int nt2 = 0; nt2 < 2; nt2++) {
      as_[mt][nt2] = (f32x4){0.f, 0.f, 0.f, 0.f};
      ap_[mt][nt2] = (f32x4){0.f, 0.f, 0.f, 0.f};
    }
  #pragma unroll
  for (int nt2 = 0; nt2 < 2; nt2++) {
    int col = 32 * w + 16 * nt2 + lr;
    bf16x8 bs = *(const bf16x8*)&Wfb_l[col * 32 + lg * 8];
    bf16x8 bp = *(const bf16x8*)&Wfb_l[(128 + col) * 32 + lg * 8];
    #pragma unroll
    for (int mt = 0; mt < 4; mt++) {
      as_[mt][nt2] = __builtin_amdgcn_mfma_f32_16x16x32_bf16(af[mt], bs, as_[mt][nt2], 0, 0, 0);
      ap_[mt][nt2] = __builtin_amdgcn_mfma_f32_16x16x32_bf16(af[mt], bp, ap_[mt][nt2], 0, 0, 0);
    }
  }

  float qs[2] = {0.f, 0.f}, q1[2] = {0.f, 0.f}, q2[2] = {0.f, 0.f}, q3[2] = {0.f, 0.f};
  #pragma unroll
  for (int mt = 0; mt < 4; mt++) {
    #pragma unroll
    for (int r = 0; r < 4; r++) {
      int n = 16 * mt + 4 * lg + r;
      float4 dv = *(const float4*)&d3l[n][0];
      #pragma unroll
      for (int nt2 = 0; nt2 < 2; nt2++) {
        int f = 32 * w + 16 * nt2 + lr;
        float yv = __bfloat162float(yjl[n * 132 + f]);
        qs[nt2] += yv * as_[mt][nt2][r];
        float pw = yv * ap_[mt][nt2][r];
        q1[nt2] += dv.y * pw;
        q2[nt2] += dv.z * pw;
        q3[nt2] += dv.w * pw;
      }
    }
  }
  #pragma unroll
  for (int nt2 = 0; nt2 < 2; nt2++) {
    float a = qs[nt2], b1 = q1[nt2], b2 = q2[nt2], b3 = q3[nt2];
    a  += __shfl_xor(a, 16);  a  += __shfl_xor(a, 32);
    b1 += __shfl_xor(b1, 16); b1 += __shfl_xor(b1, 32);
    b2 += __shfl_xor(b2, 16); b2 += __shfl_xor(b2, 32);
    b3 += __shfl_xor(b3, 16); b3 += __shfl_xor(b3, 32);
    if (lg == 0)
      cOut[atom * NF + 32 * w + 16 * nt2 + lr] = a + b1 * b1 + b2 * b2 + b3 * b3;
  }
}

// ---------------- split-key flash attn + hv + residual ----------------
// grid: (NB*16) blocks of 256; wave w owns key-chunk w and output cols [32w,32w+32)
__global__ __launch_bounds__(256) void k_attn3(
    const __hip_bfloat16* __restrict__ Qw, const __hip_bfloat16* __restrict__ Kw,
    const __hip_bfloat16* __restrict__ VwT, const float* __restrict__ amask,
    const float* __restrict__ Cb, const __hip_bfloat16* __restrict__ WTf2o,
    const float* __restrict__ bf2o_l, const __hip_bfloat16* __restrict__ WTd,
    const float* __restrict__ bd_l, float* __restrict__ x) {
  __shared__ char smem[34816];
  float* Ocomb = (float*)smem;                       // [4][16][132] f32 = 33792 B
  float* mwl = (float*)(smem + 33792);               // [4][16]
  float* swl = (float*)(smem + 34048);               // [4][16]
  int tid = threadIdx.x;
  int b = blockIdx.x >> 4, qt = blockIdx.x & 15;
  int w = tid >> 6, l = tid & 63, lr = l & 15, lg = l >> 4;
  int qbase = b * NA + qt * 16;
  const float scale = 0.08838834764831845f;

  // Q A-frags (16 shared rows)
  bf16x8 qf[4];
  #pragma unroll
  for (int ks = 0; ks < 4; ks++)
    qf[ks] = *(const bf16x8*)&Qw[(qbase + lr) * NF + ks * 32 + lg * 8];

  // QK^T for this wave's 64-key chunk, K B-frags direct from global
  f32x4 sacc[4];
  #pragma unroll
  for (int ntc = 0; ntc < 4; ntc++) sacc[ntc] = (f32x4){0.f, 0.f, 0.f, 0.f};
  #pragma unroll
  for (int ks = 0; ks < 4; ks++)
    #pragma unroll
    for (int ntc = 0; ntc < 4; ntc++) {
      bf16x8 kf = *(const bf16x8*)&Kw[(b * NA + w * 64 + ntc * 16 + lr) * NF + ks * 32 + lg * 8];
      sacc[ntc] = __builtin_amdgcn_mfma_f32_16x16x32_bf16(qf[ks], kf, sacc[ntc], 0, 0, 0);
    }

  float kam[4];
  #pragma unroll
  for (int ntc = 0; ntc < 4; ntc++)
    kam[ntc] = (1.0f - amask[b * NA + w * 64 + ntc * 16 + lr]) * (-1e9f);

  // single-chunk softmax (no online rescale)
  float mw_[4], sw_[4], plv[4][4];
  #pragma unroll
  for (int r = 0; r < 4; r++) {
    float lv[4], cm = -1e30f;
    #pragma unroll
    for (int ntc = 0; ntc < 4; ntc++) {
      lv[ntc] = sacc[ntc][r] * scale + kam[ntc];
      cm = fmaxf(cm, lv[ntc]);
    }
    cm = fmaxf(cm, __shfl_xor(cm, 1)); cm = fmaxf(cm, __shfl_xor(cm, 2));
    cm = fmaxf(cm, __shfl_xor(cm, 4)); cm = fmaxf(cm, __shfl_xor(cm, 8));
    float ps = 0.f;
    #pragma unroll
    for (int ntc = 0; ntc < 4; ntc++) {
      float p = expf(lv[ntc] - cm);
      plv[ntc][r] = p;
      ps += p;
    }
    ps += __shfl_xor(ps, 1); ps += __shfl_xor(ps, 2);
    ps += __shfl_xor(ps, 4); ps += __shfl_xor(ps, 8);
    mw_[r] = cm; sw_[r] = ps;
  }

  // P -> per-wave LDS (16x64, stride 68 u16: injective, conflict-free)
  __hip_bfloat16* Pw = (__hip_bfloat16*)smem + w * 16 * 68;
  #pragma unroll
  for (int ntc = 0; ntc < 4; ntc++)
    #pragma unroll
    for (int r = 0; r < 4; r++)
      Pw[(4 * lg + r) * 68 + ntc * 16 + lr] = __float2bfloat16(plv[ntc][r]);
  bf16x8 pf[2];
  #pragma unroll
  for (int s2 = 0; s2 < 2; s2++)
    pf[s2] = *(const bf16x8*)&Pw[lr * 68 + s2 * 32 + lg * 8];

  // PV: V^T B-frags direct from global VwT[b][f][key]
  f32x4 O[8];
  #pragma unroll
  for (int nt = 0; nt < 8; nt++) O[nt] = (f32x4){0.f, 0.f, 0.f, 0.f};
  #pragma unroll
  for (int s2 = 0; s2 < 2; s2++)
    #pragma unroll
    for (int nt = 0; nt < 8; nt++) {
      bf16x8 vf = *(const bf16x8*)&VwT[(b * NF + nt * 16 + lr) * NA + w * 64 + s2 * 32 + lg * 8];
      O[nt] = __builtin_amdgcn_mfma_f32_16x16x32_bf16(pf[s2], vf, O[nt], 0, 0, 0);
    }

  __syncthreads();   // Plds dead; Ocomb region reuse
  #pragma unroll
  for (int nt = 0; nt < 8; nt++)
    #pragma unroll
    for (int r = 0; r < 4; r++)
      Ocomb[(w * 16 + 4 * lg + r) * 132 + nt * 16 + lr] = O[nt][r];
  if (lr == 0) {
    #pragma unroll
    for (int r = 0; r < 4; r++) {
      mwl[w * 16 + 4 * lg + r] = mw_[r];
      swl[w * 16 + 4 * lg + r] = sw_[r];
    }
  }
  __syncthreads();

  // combine partial flash states; this wave outputs cols [32w, 32w+32)
  float Of[2][4], inv_[4];
  #pragma unroll
  for (int r = 0; r < 4; r++) {
    int row = 4 * lg + r;
    float m0 = mwl[row], m1 = mwl[16 + row], m2 = mwl[32 + row], m3 = mwl[48 + row];
    float m = fmaxf(fmaxf(m0, m1), fmaxf(m2, m3));
    float e0 = expf(m0 - m), e1 = expf(m1 - m), e2 = expf(m2 - m), e3 = expf(m3 - m);
    float s = swl[row] * e0 + swl[16 + row] * e1 + swl[32 + row] * e2 + swl[48 + row] * e3;
    inv_[r] = amask[qbase + row] / s;
    #pragma unroll
    for (int j = 0; j < 2; j++) {
      int col = (2 * w + j) * 16 + lr;
      Of[j][r] = Ocomb[row * 132 + col] * e0 + Ocomb[(16 + row) * 132 + col] * e1
               + Ocomb[(32 + row) * 132 + col] * e2 + Ocomb[(48 + row) * 132 + col] * e3;
    }
  }
  __syncthreads();   // Ocomb dead; hLDS region reuse

  // hv: h = ssp(c@Wf2o+b) (wave cols 32w..32w+31), roundtrip, v = h@Wd+b
  __hip_bfloat16* hLDS = (__hip_bfloat16*)smem;      // [16][132] u16 (stride > 128!)
  {
    bf16x8 cfr[4];
    const float* cr = Cb + (qbase + lr) * NF;
    #pragma unroll
    for (int ks = 0; ks < 4; ks++) {
      int k0 = ks * 32 + lg * 8;
      float4 a = *(const float4*)&cr[k0];
      float4 c = *(const float4*)&cr[k0 + 4];
      bf16x8 t;
      t[0] = (short)f2bf(a.x); t[1] = (short)f2bf(a.y);
      t[2] = (short)f2bf(a.z); t[3] = (short)f2bf(a.w);
      t[4] = (short)f2bf(c.x); t[5] = (short)f2bf(c.y);
      t[6] = (short)f2bf(c.z); t[7] = (short)f2bf(c.w);
      cfr[ks] = t;
    }
    f32x4 hacc[2];
    hacc[0] = (f32x4){0.f, 0.f, 0.f, 0.f};
    hacc[1] = (f32x4){0.f, 0.f, 0.f, 0.f};
    #pragma unroll
    for (int ks = 0; ks < 4; ks++)
      #pragma unroll
      for (int j = 0; j < 2; j++) {
        bf16x8 bfr = *(const bf16x8*)(WTf2o + ((2 * w + j) * 16 + lr) * NF + ks * 32 + lg * 8);
        hacc[j] = __builtin_amdgcn_mfma_f32_16x16x32_bf16(cfr[ks], bfr, hacc[j], 0, 0, 0);
      }
    #pragma unroll
    for (int j = 0; j < 2; j++) {
      int col = (2 * w + j) * 16 + lr;
      float bv = bf2o_l[col];
      #pragma unroll
      for (int r = 0; r < 4; r++)
        hLDS[(4 * lg + r) * 132 + col] = __float2bfloat16(sspf(hacc[j][r] + bv));
    }
  }
  __syncthreads();
  {
    bf16x8 hfr[4];
    #pragma unroll
    for (int ks = 0; ks < 4; ks++)
      hfr[ks] = *(const bf16x8*)&hLDS[lr * 132 + ks * 32 + lg * 8];
    f32x4 vacc[2];
    vacc[0] = (f32x4){0.f, 0.f, 0.f, 0.f};
    vacc[1] = (f32x4){0.f, 0.f, 0.f, 0.f};
    #pragma unroll
    for (int ks = 0; ks < 4; ks++)
      #pragma unroll
      for (int j = 0; j < 2; j++) {
        bf16x8 bfr = *(const bf16x8*)(WTd + ((2 * w + j) * 16 + lr) * NF + ks * 32 + lg * 8);
        vacc[j] = __builtin_amdgcn_mfma_f32_16x16x32_bf16(hfr[ks], bfr, vacc[j], 0, 0, 0);
      }
    // x += v + n
    #pragma unroll
    for (int r = 0; r < 4; r++) {
      int qg = qbase + 4 * lg + r;
      #pragma unroll
      for (int j = 0; j < 2; j++) {
        int col = (2 * w + j) * 16 + lr;
        x[qg * NF + col] += vacc[j][r] + bd_l[col] + Of[j][r] * inv_[r];
      }
    }
  }
}

// ---------------- host launch ----------------
extern "C" void kernel_launch(void* const* d_in, const int* in_sizes, int n_in,
                              void* d_out, int out_size, void* d_ws, size_t ws_size,
                              hipStream_t stream) {
  const float* pos   = (const float*)d_in[0];
  const float* nmask = (const float*)d_in[1];
  const float* amask = (const float*)d_in[2];
  const float* emb   = (const float*)d_in[3];
  const float* Wfs   = (const float*)d_in[4];
  const float* Wfp   = (const float*)d_in[5];
  const float* Win   = (const float*)d_in[6];
  const float* Wf2o  = (const float*)d_in[7];
  const float* bf2o  = (const float*)d_in[8];
  const float* Wd    = (const float*)d_in[9];
  const float* bd    = (const float*)d_in[10];
  const float* Wq    = (const float*)d_in[11];
  const float* Wk    = (const float*)d_in[12];
  const float* Wv    = (const float*)d_in[13];
  const int*   Z     = (const int*)d_in[14];
  const int*   nbrs  = (const int*)d_in[15];

  float* x = (float*)d_out;
  float* wsf = (float*)d_ws;
  const int S = NATOM * NF;                               // 524288
  float* Cb = wsf;                                        // S f32
  __hip_bfloat16* ybf = (__hip_bfloat16*)(wsf + S);
  __hip_bfloat16* Qw  = ybf + S;
  __hip_bfloat16* Kw  = Qw + S;
  __hip_bfloat16* VwT = Kw + S;                           // [b][f][row]
  __hip_bfloat16* WT  = VwT + S;                          // 18*16384 bf16
  __hip_bfloat16* Wfb = WT + 18 * 16384;                  // 24576 bf16

  k_init<<<dim3(3296), dim3(256), 0, stream>>>(
      Z, emb, Win, Wf2o, Wd, Wq, Wk, Wv, Wfs, Wfp, x, WT, Wfb);

  for (int l = 0; l < 3; l++) {
    const __hip_bfloat16* WTl = WT + l * 6 * 16384;

    k_proj<<<dim3(256), dim3(256), 0, stream>>>(x, amask, WTl, ybf, Qw, Kw, VwT);
    k_filter_mfma<<<dim3(NATOM), dim3(256), 0, stream>>>(
        ybf, nbrs, pos, nmask, Wfb + l * 8192, Cb);
    k_attn3<<<dim3(NB * 16), dim3(256), 0, stream>>>(
        Qw, Kw, VwT, amask, Cb, WTl + 16384, bf2o + l * NF,
        WTl + 2 * 16384, bd + l * NF, x);
  }
}

// Round 9
// 191.516 us; speedup vs baseline: 3.0498x; 1.0762x over previous
//
#include <hip/hip_runtime.h>
#include <hip/hip_bf16.h>
#include <math.h>

// TbpNet: B=16, A=256, NBH=64, F=128, K=25, L=3.
// R8: 8 dispatches. fa = filter(4096 blocks) + attn-core(256 blocks) in one
//     dispatch (attn -> Nb, P-share combine, no Ocomb). hv+residual moved into
//     next layer's proj (phase A) / k_final. Embed inlined in proj L0.
#define NB   16
#define NA   256
#define NNBH 64
#define NF   128
#define NK   25
#define NATOM (NB*NA)   // 4096

typedef __attribute__((ext_vector_type(4))) float f32x4;
typedef __attribute__((ext_vector_type(8))) short bf16x8;

__device__ __constant__ float BINOM_C[25] = {
  1.f, 24.f, 276.f, 2024.f, 10626.f, 42504.f, 134596.f, 346104.f,
  735471.f, 1307504.f, 1961256.f, 2496144.f, 2704156.f, 2496144.f,
  1961256.f, 1307504.f, 735471.f, 346104.f, 134596.f, 42504.f,
  10626.f, 2024.f, 276.f, 24.f, 1.f
};

__device__ __forceinline__ float sspf(float x) {
  float t = (x > 20.f) ? x : log1pf(expf(x));
  return t - 0.69314718055994531f;
}
__device__ __forceinline__ unsigned short f2bf(float x) {
  __hip_bfloat16 h = __float2bfloat16(x);
  return *(unsigned short*)&h;
}

// ---------------- init: WT prep + Wfb prep (weights only) ----------------
__global__ __launch_bounds__(256) void k_init(
    const float* __restrict__ Win, const float* __restrict__ Wf2o,
    const float* __restrict__ Wd, const float* __restrict__ Wq,
    const float* __restrict__ Wk, const float* __restrict__ Wv,
    const float* __restrict__ Wfs, const float* __restrict__ Wfp,
    __hip_bfloat16* __restrict__ WT, __hip_bfloat16* __restrict__ Wfb) {
  int bid = blockIdx.x, tid = threadIdx.x;
  if (bid < 1152) {
    int idx = bid * 256 + tid;               // 18*16384
    int e = idx & 16383; int m = idx >> 14;
    int l = m / 6, wsel = m - l * 6;
    const float* src = (wsel == 0) ? Win : (wsel == 1) ? Wf2o : (wsel == 2) ? Wd
                      : (wsel == 3) ? Wq : (wsel == 4) ? Wk : Wv;
    int k = e >> 7, col = e & 127;
    WT[m * 16384 + col * 128 + k] = __float2bfloat16(src[l * NF * NF + k * NF + col]);
  } else {
    int idx = (bid - 1152) * 256 + tid;      // 3*2*128*32 = 24576
    int k = idx & 31, f = (idx >> 5) & 127, s = (idx >> 12) & 1, l = idx >> 13;
    float v = 0.f;
    if (k < NK) v = (s ? Wfp : Wfs)[l * NK * NF + k * NF + f];
    Wfb[idx] = __float2bfloat16(v);          // [l][s][f][k]
  }
}

// ---------------- proj: [phase A: hv(prev layer)+residual -> x_new] + QKVY ----
template<int HV>
__global__ __launch_bounds__(256) void k_proj(
    const float* __restrict__ xg, const int* __restrict__ Z,
    const float* __restrict__ emb,
    const float* __restrict__ Cb, const float* __restrict__ Nb,
    const __hip_bfloat16* __restrict__ WTf2o_p, const float* __restrict__ bf2o_p,
    const __hip_bfloat16* __restrict__ WTd_p, const float* __restrict__ bd_p,
    const float* __restrict__ amask, const __hip_bfloat16* __restrict__ WTl,
    float* __restrict__ xout,
    __hip_bfloat16* __restrict__ ybf, __hip_bfloat16* __restrict__ Qw,
    __hip_bfloat16* __restrict__ Kw, __hip_bfloat16* __restrict__ VwT) {
  __shared__ __hip_bfloat16 hLDS[16 * 132];
  __shared__ float xLDS[16 * 133];
  int tid = threadIdx.x;
  int z = tid >> 6, l = tid & 63, lr = l & 15, lg = l >> 4;
  int rbase = blockIdx.x * 16;

  if (HV) {
    // phase A: h = ssp(c@Wf2o+b); v = h@Wd+b; x_new = x_old + v + n
    bf16x8 cfr[4];
    const float* cr = Cb + (rbase + lr) * NF;
    #pragma unroll
    for (int ks = 0; ks < 4; ks++) {
      int k0 = ks * 32 + lg * 8;
      float4 a = *(const float4*)&cr[k0];
      float4 c = *(const float4*)&cr[k0 + 4];
      bf16x8 t;
      t[0] = (short)f2bf(a.x); t[1] = (short)f2bf(a.y);
      t[2] = (short)f2bf(a.z); t[3] = (short)f2bf(a.w);
      t[4] = (short)f2bf(c.x); t[5] = (short)f2bf(c.y);
      t[6] = (short)f2bf(c.z); t[7] = (short)f2bf(c.w);
      cfr[ks] = t;
    }
    f32x4 hacc[2];
    hacc[0] = (f32x4){0.f, 0.f, 0.f, 0.f};
    hacc[1] = (f32x4){0.f, 0.f, 0.f, 0.f};
    #pragma unroll
    for (int ks = 0; ks < 4; ks++)
      #pragma unroll
      for (int j = 0; j < 2; j++) {
        bf16x8 bfr = *(const bf16x8*)(WTf2o_p + ((2 * z + j) * 16 + lr) * NF + ks * 32 + lg * 8);
        hacc[j] = __builtin_amdgcn_mfma_f32_16x16x32_bf16(cfr[ks], bfr, hacc[j], 0, 0, 0);
      }
    #pragma unroll
    for (int j = 0; j < 2; j++) {
      int col = (2 * z + j) * 16 + lr;
      float bv = bf2o_p[col];
      #pragma unroll
      for (int r = 0; r < 4; r++)
        hLDS[(4 * lg + r) * 132 + col] = __float2bfloat16(sspf(hacc[j][r] + bv));
    }
    __syncthreads();
    bf16x8 hfr[4];
    #pragma unroll
    for (int ks = 0; ks < 4; ks++)
      hfr[ks] = *(const bf16x8*)&hLDS[lr * 132 + ks * 32 + lg * 8];
    f32x4 vacc[2];
    vacc[0] = (f32x4){0.f, 0.f, 0.f, 0.f};
    vacc[1] = (f32x4){0.f, 0.f, 0.f, 0.f};
    #pragma unroll
    for (int ks = 0; ks < 4; ks++)
      #pragma unroll
      for (int j = 0; j < 2; j++) {
        bf16x8 bfr = *(const bf16x8*)(WTd_p + ((2 * z + j) * 16 + lr) * NF + ks * 32 + lg * 8);
        vacc[j] = __builtin_amdgcn_mfma_f32_16x16x32_bf16(hfr[ks], bfr, vacc[j], 0, 0, 0);
      }
    #pragma unroll
    for (int j = 0; j < 2; j++) {
      int col = (2 * z + j) * 16 + lr;
      float bv = bd_p[col];
      #pragma unroll
      for (int r = 0; r < 4; r++) {
        int row = rbase + 4 * lg + r;
        float xv = xg[row * NF + col] + vacc[j][r] + bv + Nb[row * NF + col];
        xout[row * NF + col] = xv;
        xLDS[(4 * lg + r) * 133 + col] = xv;
      }
    }
    __syncthreads();
  } else {
    // L0: x = embedding gather
    int rr = tid >> 4, c0 = (tid & 15) * 8;
    int row = rbase + rr;
    const float* er = emb + Z[row] * NF;
    float4 a = *(const float4*)&er[c0];
    float4 b = *(const float4*)&er[c0 + 4];
    *(float4*)&xout[row * NF + c0] = a;
    *(float4*)&xout[row * NF + c0 + 4] = b;
    xLDS[rr * 133 + c0 + 0] = a.x; xLDS[rr * 133 + c0 + 1] = a.y;
    xLDS[rr * 133 + c0 + 2] = a.z; xLDS[rr * 133 + c0 + 3] = a.w;
    xLDS[rr * 133 + c0 + 4] = b.x; xLDS[rr * 133 + c0 + 5] = b.y;
    xLDS[rr * 133 + c0 + 6] = b.z; xLDS[rr * 133 + c0 + 7] = b.w;
    __syncthreads();
  }

  // phase B: projections. wave z: 0->y, 1->q, 2->k, 3->v(T)
  float am = (z > 0) ? amask[rbase + lr] : 1.0f;
  bf16x8 afr[4];
  #pragma unroll
  for (int ks = 0; ks < 4; ks++) {
    int k0 = ks * 32 + lg * 8;
    bf16x8 t;
    #pragma unroll
    for (int jj = 0; jj < 8; jj++)
      t[jj] = (short)f2bf(xLDS[lr * 133 + k0 + jj] * am);
    afr[ks] = t;
  }
  const __hip_bfloat16* WT = WTl + ((z == 0) ? 0 : (z + 2)) * (NF * NF);

  f32x4 acc[8];
  #pragma unroll
  for (int nt = 0; nt < 8; nt++) acc[nt] = (f32x4){0.f, 0.f, 0.f, 0.f};
  #pragma unroll
  for (int ks = 0; ks < 4; ks++)
    #pragma unroll
    for (int nt = 0; nt < 8; nt++) {
      bf16x8 bfr = *(const bf16x8*)(WT + (nt * 16 + lr) * NF + ks * 32 + lg * 8);
      acc[nt] = __builtin_amdgcn_mfma_f32_16x16x32_bf16(afr[ks], bfr, acc[nt], 0, 0, 0);
    }

  if (z < 3) {
    __hip_bfloat16* out = (z == 0) ? ybf : (z == 1) ? Qw : Kw;
    #pragma unroll
    for (int nt = 0; nt < 8; nt++) {
      int col = nt * 16 + lr;
      #pragma unroll
      for (int r = 0; r < 4; r++) {
        int orow = rbase + lg * 4 + r;
        float o = acc[nt][r];
        if (z > 0) o = sspf(o);
        out[orow * NF + col] = __float2bfloat16(o);
      }
    }
  } else {
    int b = blockIdx.x >> 4;
    int ar0 = (blockIdx.x & 15) * 16 + lg * 4;
    #pragma unroll
    for (int nt = 0; nt < 8; nt++) {
      int col = nt * 16 + lr;
      #pragma unroll
      for (int r = 0; r < 4; r++)
        VwT[(b * NF + col) * NA + ar0 + r] = __float2bfloat16(sspf(acc[nt][r]));
    }
  }
}

// ---------------- fa: blocks<4096 filter, else attn-core -> Nb ----------------
__global__ __launch_bounds__(256) void k_fa(
    const __hip_bfloat16* __restrict__ ybf, const int* __restrict__ nbrs,
    const float* __restrict__ pos, const float* __restrict__ nmask,
    const __hip_bfloat16* __restrict__ Wfb_l, float* __restrict__ cOut,
    const __hip_bfloat16* __restrict__ Qw, const __hip_bfloat16* __restrict__ Kw,
    const __hip_bfloat16* __restrict__ VwT, const float* __restrict__ amask,
    float* __restrict__ Nb) {
  __shared__ char smem[23296];
  int tid = threadIdx.x;
  int lane = tid & 63, w = tid >> 6, lr = lane & 15, lg = lane >> 4;

  if (blockIdx.x < 4096) {
    // ================= filter =================
    __hip_bfloat16* FF  = (__hip_bfloat16*)smem;            // [64][40]
    __hip_bfloat16* yjl = (__hip_bfloat16*)(smem + 5120);   // [64][132]
    float (*d3l)[4]     = (float(*)[4])(smem + 22016);      // [64][4]
    int* jl             = (int*)(smem + 23040);             // [64]
    int atom = blockIdx.x, brow = atom & ~(NA - 1);

    {
      int n = tid & 63;
      int j = nbrs[atom * NNBH + n];
      float px = pos[(brow + j) * 3 + 0] - pos[atom * 3 + 0];
      float py = pos[(brow + j) * 3 + 1] - pos[atom * 3 + 1];
      float pz = pos[(brow + j) * 3 + 2] - pos[atom * 3 + 2];
      float m = nmask[atom * NNBH + n];
      float r = sqrtf(px * px + py * py + pz * pz + 1e-12f) * m;
      float inv = 1.0f / (r + 1e-9f);
      float fc = (r < 5.0f) ? (0.5f * cosf(0.62831853071795865f * r) + 0.5f) * m : 0.0f;
      float xe = expf(-r);
      float l1 = log2f(xe + 1e-10f);
      float l2 = log2f(1.0f - xe + 1e-10f);
      if (tid < NNBH) {
        jl[n] = j;
        d3l[n][0] = 0.f;
        d3l[n][1] = px * inv;
        d3l[n][2] = py * inv;
        d3l[n][3] = pz * inv;
      }
      int kq = tid >> 6;
      bf16x8 v;
      #pragma unroll
      for (int j8 = 0; j8 < 8; j8++) {
        int k = kq * 8 + j8;
        float val = 0.f;
        if (k < NK)
          val = BINOM_C[k] * exp2f((float)k * l1 + (float)(24 - k) * l2) * fc;
        v[j8] = (short)f2bf(val);
      }
      *(bf16x8*)&FF[n * 40 + kq * 8] = v;
    }
    __syncthreads();

    {
      int n = tid >> 2, c0 = (tid & 3) * 32;
      const __hip_bfloat16* src = &ybf[(brow + jl[n]) * NF + c0];
      #pragma unroll
      for (int i = 0; i < 4; i++) {
        uint4 u = *(const uint4*)(src + i * 8);
        uint2* dst = (uint2*)&yjl[n * 132 + c0 + i * 8];
        dst[0] = make_uint2(u.x, u.y);
        dst[1] = make_uint2(u.z, u.w);
      }
    }
    __syncthreads();

    bf16x8 af[4];
    #pragma unroll
    for (int mt = 0; mt < 4; mt++)
      af[mt] = *(bf16x8*)&FF[(16 * mt + lr) * 40 + lg * 8];

    f32x4 as_[4][2], ap_[4][2];
    #pragma unroll
    for (int mt = 0; mt < 4; mt++)
      #pragma unroll
      for (int nt2 = 0; nt2 < 2; nt2++) {
        as_[mt][nt2] = (f32x4){0.f, 0.f, 0.f, 0.f};
        ap_[mt][nt2] = (f32x4){0.f, 0.f, 0.f, 0.f};
      }
    #pragma unroll
    for (int nt2 = 0; nt2 < 2; nt2++) {
      int col = 32 * w + 16 * nt2 + lr;
      bf16x8 bs = *(const bf16x8*)&Wfb_l[col * 32 + lg * 8];
      bf16x8 bp = *(const bf16x8*)&Wfb_l[(128 + col) * 32 + lg * 8];
      #pragma unroll
      for (int mt = 0; mt < 4; mt++) {
        as_[mt][nt2] = __builtin_amdgcn_mfma_f32_16x16x32_bf16(af[mt], bs, as_[mt][nt2], 0, 0, 0);
        ap_[mt][nt2] = __builtin_amdgcn_mfma_f32_16x16x32_bf16(af[mt], bp, ap_[mt][nt2], 0, 0, 0);
      }
    }

    float qs[2] = {0.f, 0.f}, q1[2] = {0.f, 0.f}, q2[2] = {0.f, 0.f}, q3[2] = {0.f, 0.f};
    #pragma unroll
    for (int mt = 0; mt < 4; mt++) {
      #pragma unroll
      for (int r = 0; r < 4; r++) {
        int n = 16 * mt + 4 * lg + r;
        float4 dv = *(const float4*)&d3l[n][0];
        #pragma unroll
        for (int nt2 = 0; nt2 < 2; nt2++) {
          int f = 32 * w + 16 * nt2 + lr;
          float yv = __bfloat162float(yjl[n * 132 + f]);
          qs[nt2] += yv * as_[mt][nt2][r];
          float pw = yv * ap_[mt][nt2][r];
          q1[nt2] += dv.y * pw;
          q2[nt2] += dv.z * pw;
          q3[nt2] += dv.w * pw;
        }
      }
    }
    #pragma unroll
    for (int nt2 = 0; nt2 < 2; nt2++) {
      float a = qs[nt2], b1 = q1[nt2], b2 = q2[nt2], b3 = q3[nt2];
      a  += __shfl_xor(a, 16);  a  += __shfl_xor(a, 32);
      b1 += __shfl_xor(b1, 16); b1 += __shfl_xor(b1, 32);
      b2 += __shfl_xor(b2, 16); b2 += __shfl_xor(b2, 32);
      b3 += __shfl_xor(b3, 16); b3 += __shfl_xor(b3, 32);
      if (lg == 0)
        cOut[atom * NF + 32 * w + 16 * nt2 + lr] = a + b1 * b1 + b2 * b2 + b3 * b3;
    }
  } else {
    // ================= attn-core -> Nb =================
    __hip_bfloat16* Plds = (__hip_bfloat16*)smem;           // [16][260]
    float* mwl = (float*)(smem + 8320);                     // [4][16]
    float* swl = (float*)(smem + 8576);                     // [4][16]
    int bb = blockIdx.x - 4096;
    int b = bb >> 4, qt = bb & 15;
    int qbase = b * NA + qt * 16;
    const float scale = 0.08838834764831845f;

    bf16x8 qf[4];
    #pragma unroll
    for (int ks = 0; ks < 4; ks++)
      qf[ks] = *(const bf16x8*)&Qw[(qbase + lr) * NF + ks * 32 + lg * 8];

    // QK^T for this wave's 64-key chunk (K frags direct from global)
    f32x4 sacc[4];
    #pragma unroll
    for (int ntc = 0; ntc < 4; ntc++) sacc[ntc] = (f32x4){0.f, 0.f, 0.f, 0.f};
    #pragma unroll
    for (int ks = 0; ks < 4; ks++)
      #pragma unroll
      for (int ntc = 0; ntc < 4; ntc++) {
        bf16x8 kf = *(const bf16x8*)&Kw[(b * NA + w * 64 + ntc * 16 + lr) * NF + ks * 32 + lg * 8];
        sacc[ntc] = __builtin_amdgcn_mfma_f32_16x16x32_bf16(qf[ks], kf, sacc[ntc], 0, 0, 0);
      }

    float kam[4];
    #pragma unroll
    for (int ntc = 0; ntc < 4; ntc++)
      kam[ntc] = (1.0f - amask[b * NA + w * 64 + ntc * 16 + lr]) * (-1e9f);

    // chunk softmax: write unnormalized P + (m,s) per row
    #pragma unroll
    for (int r = 0; r < 4; r++) {
      float lv[4], cm = -1e30f;
      #pragma unroll
      for (int ntc = 0; ntc < 4; ntc++) {
        lv[ntc] = sacc[ntc][r] * scale + kam[ntc];
        cm = fmaxf(cm, lv[ntc]);
      }
      cm = fmaxf(cm, __shfl_xor(cm, 1)); cm = fmaxf(cm, __shfl_xor(cm, 2));
      cm = fmaxf(cm, __shfl_xor(cm, 4)); cm = fmaxf(cm, __shfl_xor(cm, 8));
      float ps = 0.f;
      #pragma unroll
      for (int ntc = 0; ntc < 4; ntc++) {
        float p = expf(lv[ntc] - cm);
        Plds[(4 * lg + r) * 260 + w * 64 + ntc * 16 + lr] = __float2bfloat16(p);
        ps += p;
      }
      ps += __shfl_xor(ps, 1); ps += __shfl_xor(ps, 2);
      ps += __shfl_xor(ps, 4); ps += __shfl_xor(ps, 8);
      if (lr == 0) {
        mwl[w * 16 + 4 * lg + r] = cm;
        swl[w * 16 + 4 * lg + r] = ps;
      }
    }
    __syncthreads();

    // combine factors per row
    float ec[4][4], inv_[4];
    #pragma unroll
    for (int r = 0; r < 4; r++) {
      int row = 4 * lg + r;
      float m0 = mwl[row], m1 = mwl[16 + row], m2 = mwl[32 + row], m3 = mwl[48 + row];
      float M = fmaxf(fmaxf(m0, m1), fmaxf(m2, m3));
      float e0 = expf(m0 - M), e1 = expf(m1 - M), e2 = expf(m2 - M), e3 = expf(m3 - M);
      ec[0][r] = e0; ec[1][r] = e1; ec[2][r] = e2; ec[3][r] = e3;
      float s = swl[row] * e0 + swl[16 + row] * e1 + swl[32 + row] * e2 + swl[48 + row] * e3;
      inv_[r] = amask[qbase + row] / s;
    }

    // PV over all 4 chunks for this wave's 32 cols, defer-scaled combine
    f32x4 O[2];
    O[0] = (f32x4){0.f, 0.f, 0.f, 0.f};
    O[1] = (f32x4){0.f, 0.f, 0.f, 0.f};
    #pragma unroll
    for (int c = 0; c < 4; c++) {
      bf16x8 pf[2];
      #pragma unroll
      for (int s2 = 0; s2 < 2; s2++)
        pf[s2] = *(const bf16x8*)&Plds[lr * 260 + c * 64 + s2 * 32 + lg * 8];
      f32x4 tc[2];
      tc[0] = (f32x4){0.f, 0.f, 0.f, 0.f};
      tc[1] = (f32x4){0.f, 0.f, 0.f, 0.f};
      #pragma unroll
      for (int s2 = 0; s2 < 2; s2++)
        #pragma unroll
        for (int j = 0; j < 2; j++) {
          bf16x8 vf = *(const bf16x8*)&VwT[(b * NF + (2 * w + j) * 16 + lr) * NA + c * 64 + s2 * 32 + lg * 8];
          tc[j] = __builtin_amdgcn_mfma_f32_16x16x32_bf16(pf[s2], vf, tc[j], 0, 0, 0);
        }
      #pragma unroll
      for (int j = 0; j < 2; j++)
        #pragma unroll
        for (int r = 0; r < 4; r++)
          O[j][r] += ec[c][r] * tc[j][r];
    }

    // n out
    #pragma unroll
    for (int r = 0; r < 4; r++) {
      int q = qbase + 4 * lg + r;
      #pragma unroll
      for (int j = 0; j < 2; j++) {
        int col = (2 * w + j) * 16 + lr;
        Nb[q * NF + col] = O[j][r] * inv_[r];
      }
    }
  }
}

// ---------------- final: hv(L2) + residual -> x (d_out) ----------------
__global__ __launch_bounds__(256) void k_final(
    const float* __restrict__ Cb, const float* __restrict__ Nb,
    const __hip_bfloat16* __restrict__ WTf2o_p, const float* __restrict__ bf2o_p,
    const __hip_bfloat16* __restrict__ WTd_p, const float* __restrict__ bd_p,
    float* __restrict__ x) {
  __shared__ __hip_bfloat16 hLDS[16 * 132];
  int tid = threadIdx.x;
  int z = tid >> 6, l = tid & 63, lr = l & 15, lg = l >> 4;
  int rbase = blockIdx.x * 16;

  bf16x8 cfr[4];
  const float* cr = Cb + (rbase + lr) * NF;
  #pragma unroll
  for (int ks = 0; ks < 4; ks++) {
    int k0 = ks * 32 + lg * 8;
    float4 a = *(const float4*)&cr[k0];
    float4 c = *(const float4*)&cr[k0 + 4];
    bf16x8 t;
    t[0] = (short)f2bf(a.x); t[1] = (short)f2bf(a.y);
    t[2] = (short)f2bf(a.z); t[3] = (short)f2bf(a.w);
    t[4] = (short)f2bf(c.x); t[5] = (short)f2bf(c.y);
    t[6] = (short)f2bf(c.z); t[7] = (short)f2bf(c.w);
    cfr[ks] = t;
  }
  f32x4 hacc[2];
  hacc[0] = (f32x4){0.f, 0.f, 0.f, 0.f};
  hacc[1] = (f32x4){0.f, 0.f, 0.f, 0.f};
  #pragma unroll
  for (int ks = 0; ks < 4; ks++)
    #pragma unroll
    for (int j = 0; j < 2; j++) {
      bf16x8 bfr = *(const bf16x8*)(WTf2o_p + ((2 * z + j) * 16 + lr) * NF + ks * 32 + lg * 8);
      hacc[j] = __builtin_amdgcn_mfma_f32_16x16x32_bf16(cfr[ks], bfr, hacc[j], 0, 0, 0);
    }
  #pragma unroll
  for (int j = 0; j < 2; j++) {
    int col = (2 * z + j) * 16 + lr;
    float bv = bf2o_p[col];
    #pragma unroll
    for (int r = 0; r < 4; r++)
      hLDS[(4 * lg + r) * 132 + col] = __float2bfloat16(sspf(hacc[j][r] + bv));
  }
  __syncthreads();
  bf16x8 hfr[4];
  #pragma unroll
  for (int ks = 0; ks < 4; ks++)
    hfr[ks] = *(const bf16x8*)&hLDS[lr * 132 + ks * 32 + lg * 8];
  f32x4 vacc[2];
  vacc[0] = (f32x4){0.f, 0.f, 0.f, 0.f};
  vacc[1] = (f32x4){0.f, 0.f, 0.f, 0.f};
  #pragma unroll
  for (int ks = 0; ks < 4; ks++)
    #pragma unroll
    for (int j = 0; j < 2; j++) {
      bf16x8 bfr = *(const bf16x8*)(WTd_p + ((2 * z + j) * 16 + lr) * NF + ks * 32 + lg * 8);
      vacc[j] = __builtin_amdgcn_mfma_f32_16x16x32_bf16(hfr[ks], bfr, vacc[j], 0, 0, 0);
    }
  #pragma unroll
  for (int j = 0; j < 2; j++) {
    int col = (2 * z + j) * 16 + lr;
    float bv = bd_p[col];
    #pragma unroll
    for (int r = 0; r < 4; r++) {
      int row = rbase + 4 * lg + r;
      x[row * NF + col] += vacc[j][r] + bv + Nb[row * NF + col];
    }
  }
}

// ---------------- host launch ----------------
extern "C" void kernel_launch(void* const* d_in, const int* in_sizes, int n_in,
                              void* d_out, int out_size, void* d_ws, size_t ws_size,
                              hipStream_t stream) {
  const float* pos   = (const float*)d_in[0];
  const float* nmask = (const float*)d_in[1];
  const float* amask = (const float*)d_in[2];
  const float* emb   = (const float*)d_in[3];
  const float* Wfs   = (const float*)d_in[4];
  const float* Wfp   = (const float*)d_in[5];
  const float* Win   = (const float*)d_in[6];
  const float* Wf2o  = (const float*)d_in[7];
  const float* bf2o  = (const float*)d_in[8];
  const float* Wd    = (const float*)d_in[9];
  const float* bd    = (const float*)d_in[10];
  const float* Wq    = (const float*)d_in[11];
  const float* Wk    = (const float*)d_in[12];
  const float* Wv    = (const float*)d_in[13];
  const int*   Z     = (const int*)d_in[14];
  const int*   nbrs  = (const int*)d_in[15];

  float* x = (float*)d_out;
  float* wsf = (float*)d_ws;
  const int S = NATOM * NF;                               // 524288
  float* Cb = wsf;                                        // S f32
  float* Nb = wsf + S;                                    // S f32
  __hip_bfloat16* ybf = (__hip_bfloat16*)(wsf + 2 * S);
  __hip_bfloat16* Qw  = ybf + S;
  __hip_bfloat16* Kw  = Qw + S;
  __hip_bfloat16* VwT = Kw + S;                           // [b][f][row]
  __hip_bfloat16* WT  = VwT + S;                          // 18*16384 bf16
  __hip_bfloat16* Wfb = WT + 18 * 16384;                  // 24576 bf16

  k_init<<<dim3(1248), dim3(256), 0, stream>>>(
      Win, Wf2o, Wd, Wq, Wk, Wv, Wfs, Wfp, WT, Wfb);

  for (int l = 0; l < 3; l++) {
    const __hip_bfloat16* WTl = WT + l * 6 * 16384;
    if (l == 0)
      k_proj<0><<<dim3(256), dim3(256), 0, stream>>>(
          nullptr, Z, emb, nullptr, nullptr, nullptr, nullptr, nullptr, nullptr,
          amask, WTl, x, ybf, Qw, Kw, VwT);
    else {
      const __hip_bfloat16* WTp = WT + (l - 1) * 6 * 16384;
      k_proj<1><<<dim3(256), dim3(256), 0, stream>>>(
          x, nullptr, nullptr, Cb, Nb, WTp + 16384, bf2o + (l - 1) * NF,
          WTp + 2 * 16384, bd + (l - 1) * NF, amask, WTl, x, ybf, Qw, Kw, VwT);
    }
    k_fa<<<dim3(4096 + 256), dim3(256), 0, stream>>>(
        ybf, nbrs, pos, nmask, Wfb + l * 8192, Cb, Qw, Kw, VwT, amask, Nb);
  }
  const __hip_bfloat16* WT2 = WT + 2 * 6 * 16384;
  k_final<<<dim3(256), dim3(256), 0, stream>>>(
      Cb, Nb, WT2 + 16384, bf2o + 2 * NF, WT2 + 2 * 16384, bd + 2 * NF, x);
}